// Round 13
// baseline (654.113 us; speedup 1.0000x reference)
//
#include <hip/hip_runtime.h>

#define BB 8
#define TIN 168
#define NN 1500
#define TOUTC 24
#define TLEN 162
#define NG 32
#define NTH 1024
#define SN 2
#define TOPKK 12

// workspace offsets (in 4-byte elements)
#define OFF_M1   0
#define OFF_M2   24000
#define OFF_EW   48000
#define OFF_EB   48112
#define OFF_ADJW 48128
#define OFF_ADJI 67628
#define OFF_S16  87136      // 8*16*1500 = 192000 floats, [b][c][v]
#define OFF_PART 279136     // 8*32*16*1500 floats, [bg][c][v] channel-major
// total ws = 6,423,136 floats = 25.7 MB

__device__ __forceinline__ unsigned short f2bf(float f) {
    unsigned int u = __float_as_uint(f);
    unsigned int r = (u + 0x7fffu + ((u >> 16) & 1u)) >> 16;
    return (unsigned short)r;
}
__device__ __forceinline__ unsigned int pack2(float lo, float hi) {
    return (unsigned int)f2bf(lo) | ((unsigned int)f2bf(hi) << 16);
}
__device__ __forceinline__ float unlo(unsigned int u) { return __uint_as_float(u << 16); }
__device__ __forceinline__ float unhi(unsigned int u) { return __uint_as_float(u & 0xffff0000u); }

// ---------------- prep: m1/m2 embeddings + effective inception taps ----------------
__global__ __launch_bounds__(256) void prep_kernel(
    const float* __restrict__ e1, const float* __restrict__ e2,
    const float* __restrict__ gw1, const float* __restrict__ gb1,
    const float* __restrict__ gw2, const float* __restrict__ gb2,
    const float* __restrict__ pw, const float* __restrict__ pb,
    const float* __restrict__ tw2, const float* __restrict__ tb2,
    const float* __restrict__ tw3, const float* __restrict__ tb3,
    const float* __restrict__ tw6, const float* __restrict__ tb6,
    const float* __restrict__ tw7, const float* __restrict__ tb7,
    float* __restrict__ ws)
{
    int n = blockIdx.x * blockDim.x + threadIdx.x;
    if (n < NN) {
        float a1[16], a2[16];
        #pragma unroll
        for (int o = 0; o < 16; ++o) { a1[o] = gb1[o]; a2[o] = gb2[o]; }
        #pragma unroll
        for (int i = 0; i < 16; ++i) {
            float u = e1[n*16+i], v = e2[n*16+i];
            #pragma unroll
            for (int o = 0; o < 16; ++o) {
                a1[o] += u * gw1[i*16+o];
                a2[o] += v * gw2[i*16+o];
            }
        }
        #pragma unroll
        for (int o = 0; o < 16; ++o) {
            ws[OFF_M1 + n*16+o] = tanhf(1.5f*a1[o]);
            ws[OFF_M2 + n*16+o] = tanhf(1.5f*a2[o]);
        }
    }
    if (blockIdx.x == 0 && threadIdx.x < 16) {
        int c = threadIdx.x;
        int br = c >> 2, oc = c & 3;
        const float* tw; const float* tb; int k;
        if (br == 0)      { tw = tw2; tb = tb2; k = 2; }
        else if (br == 1) { tw = tw3; tb = tb3; k = 3; }
        else if (br == 2) { tw = tw6; tb = tb6; k = 6; }
        else              { tw = tw7; tb = tb7; k = 7; }
        for (int d = 0; d < 7; ++d) ws[OFF_EW + c*7 + d] = 0.f;
        float ebv = tb[oc];
        for (int j = 0; j < k; ++j) {
            float s = 0.f, sb = 0.f;
            for (int ic = 0; ic < 16; ++ic) {
                float w = tw[(oc*16+ic)*k + j];
                s  += w * pw[ic];
                sb += w * pb[ic];
            }
            ws[OFF_EW + c*7 + (7-k+j)] = s;
            ebv += sb;
        }
        ws[OFF_EB + c] = ebv;
    }
}

// ---------------- graph: scores in registers + shuffle-argmax top-12 ----------------
__global__ __launch_bounds__(256) void graph_kernel(
    const float* __restrict__ m1, const float* __restrict__ m2,
    float* __restrict__ adjw, int* __restrict__ adji)
{
    int v = blockIdx.x;
    int tid = threadIdx.x;
    __shared__ float wv4[4];
    __shared__ int   wi4[4];
    __shared__ int   bcast_i;
    __shared__ float m1v[16], m2v[16];
    if (tid < 16) { m1v[tid] = m1[v*16+tid]; m2v[tid] = m2[v*16+tid]; }
    __syncthreads();
    const float4* m1f = (const float4*)m1;
    const float4* m2f = (const float4*)m2;
    float sreg[6];
    #pragma unroll
    for (int u = 0; u < 6; ++u) {
        int j = tid + 256*u;
        float a = -1.f;
        if (j < NN) {
            float d = 0.f;
            #pragma unroll
            for (int q = 0; q < 4; ++q) {
                float4 r2 = m2f[j*4+q];
                float4 r1 = m1f[j*4+q];
                d += m1v[4*q+0]*r2.x - m2v[4*q+0]*r1.x;
                d += m1v[4*q+1]*r2.y - m2v[4*q+1]*r1.y;
                d += m1v[4*q+2]*r2.z - m2v[4*q+2]*r1.z;
                d += m1v[4*q+3]*r2.w - m2v[4*q+3]*r1.w;
            }
            float t = tanhf(1.5f*d);
            a = t > 0.f ? t : 0.f;
        }
        sreg[u] = a;
    }
    float lb = -1.f; int li = NN;
    #pragma unroll
    for (int u = 0; u < 6; ++u) {
        int j = tid + 256*u;
        if (j < NN && sreg[u] > lb) { lb = sreg[u]; li = j; }
    }
    const int wid = tid >> 6;
    for (int it = 0; it < TOPKK; ++it) {
        float bv = lb; int bi = li;
        #pragma unroll
        for (int off = 32; off > 0; off >>= 1) {
            float ov = __shfl_down(bv, off);
            int   oi = __shfl_down(bi, off);
            if (ov > bv || (ov == bv && oi < bi)) { bv = ov; bi = oi; }
        }
        if ((tid & 63) == 0) { wv4[wid] = bv; wi4[wid] = bi; }
        __syncthreads();
        if (tid == 0) {
            #pragma unroll
            for (int w = 1; w < 4; ++w) {
                float ov = wv4[w]; int oi = wi4[w];
                if (ov > bv || (ov == bv && oi < bi)) { bv = ov; bi = oi; }
            }
            adjw[v*13+it] = bv;
            adji[v*13+it] = bi;
            bcast_i = bi;
        }
        __syncthreads();
        int win = bcast_i;
        if (li == win) {
            #pragma unroll
            for (int u = 0; u < 6; ++u)
                if (tid + 256*u == win) sreg[u] = -1.f;
            lb = -1.f; li = NN;
            #pragma unroll
            for (int u = 0; u < 6; ++u) {
                int j = tid + 256*u;
                if (j < NN && sreg[u] > lb) { lb = sreg[u]; li = j; }
            }
        }
    }
    if (tid == 0) {
        float s = 1.f;
        #pragma unroll
        for (int it = 0; it < TOPKK; ++it) s += adjw[v*13+it];
        float inv = 1.f/s;
        #pragma unroll
        for (int it = 0; it < TOPKK; ++it) adjw[v*13+it] *= inv;
        adji[v*13+12] = v;
        adjw[v*13+12] = inv;   // normalized self-loop
    }
}

// ---------------- main: R9-proven structure at NTH=1024 (16 waves/CU) ----------------
// part is channel-major [bg][c][v]: wave stores are 256-B contiguous full lines
// (R12 showed 64-B-stride float4 RMW causes partial-line write-allocate storms).
// s-loops serialized (R9 spill fix). 1024 threads: same total wave-work per phase
// (24 wave-iters), but 16 resident waves/CU instead of 12 -> better latency hiding.
__global__ __launch_bounds__(NTH, 4) void main_kernel(
    const float* __restrict__ x,
    const float* __restrict__ ew, const float* __restrict__ eb,
    const float* __restrict__ adjw, const int* __restrict__ adji,
    float* __restrict__ part,
    const float* __restrict__ mw, const float* __restrict__ mb,
    const float* __restrict__ rw1, const float* __restrict__ rb1)
{
    // SoA by row: row r holds channels 8r..8r+7 (uint4 = 8 bf16), contiguous in v.
    __shared__ uint4 h1b[2][NN];   // 48000 B : h1 bf16
    __shared__ uint4 p1b[2][NN];   // 48000 B : hop1 bf16

    const int tid = threadIdx.x;
    const int b = blockIdx.x >> 5;
    const int g = blockIdx.x & 31;
    const int t0 = (g*TLEN) >> 5;
    const int t1 = ((g+1)*TLEN) >> 5;

    for (int t = t0; t < t1; ++t) {
        // ---- Phase A: 7-tap conv -> h1 (bf16 LDS) ----
        #pragma unroll 1
        for (int s = 0; s < SN; ++s) {
            int v = tid + NTH*s;
            if (v < NN) {
                float xv[7];
                #pragma unroll
                for (int d = 0; d < 7; ++d) xv[d] = x[(b*TIN + t + d)*NN + v];
                float h[16];
                #pragma unroll
                for (int c = 0; c < 16; ++c) {
                    float a = eb[c];
                    #pragma unroll
                    for (int d = 0; d < 7; ++d) a += ew[c*7+d]*xv[d];
                    h[c] = a > 0.f ? a : 0.f;
                }
                h1b[0][v] = make_uint4(pack2(h[0],h[1]), pack2(h[2],h[3]), pack2(h[4],h[5]), pack2(h[6],h[7]));
                h1b[1][v] = make_uint4(pack2(h[8],h[9]), pack2(h[10],h[11]), pack2(h[12],h[13]), pack2(h[14],h[15]));
            }
        }
        __syncthreads();
        // ---- Phase B: hop1 = 0.2*h1own + 0.8*A@h1 -> p1b ----
        #pragma unroll 1
        for (int s = 0; s < SN; ++s) {
            int v = tid + NTH*s;
            if (v < NN) {
                float hp[16];
                {
                    uint4 a0 = h1b[0][v], a1 = h1b[1][v];
                    unsigned int uu[8] = {a0.x,a0.y,a0.z,a0.w,a1.x,a1.y,a1.z,a1.w};
                    #pragma unroll
                    for (int i = 0; i < 8; ++i) { hp[2*i] = 0.2f*unlo(uu[i]); hp[2*i+1] = 0.2f*unhi(uu[i]); }
                }
                int base = v*13;
                #pragma unroll
                for (int j = 0; j < 13; ++j) {
                    int nb = adji[base+j];
                    float w = 0.8f*adjw[base+j];
                    uint4 b0 = h1b[0][nb], b1 = h1b[1][nb];
                    unsigned int uu[8] = {b0.x,b0.y,b0.z,b0.w,b1.x,b1.y,b1.z,b1.w};
                    #pragma unroll
                    for (int i = 0; i < 8; ++i) { hp[2*i] += w*unlo(uu[i]); hp[2*i+1] += w*unhi(uu[i]); }
                }
                p1b[0][v] = make_uint4(pack2(hp[0],hp[1]), pack2(hp[2],hp[3]), pack2(hp[4],hp[5]), pack2(hp[6],hp[7]));
                p1b[1][v] = make_uint4(pack2(hp[8],hp[9]), pack2(hp[10],hp[11]), pack2(hp[12],hp[13]), pack2(hp[14],hp[15]));
            }
        }
        __syncthreads();
        // ---- Phase C/D: hop2 gather (regs) + mw folds + rw1 ; accumulate to global ----
        #pragma unroll 1
        for (int s = 0; s < SN; ++s) {
            int v = tid + NTH*s;
            if (v < NN) {
                float y16[16];
                #pragma unroll
                for (int o = 0; o < 16; ++o) y16[o] = mb[o];
                float hop2[16];
                // own h1: hop2 base + fold mw[:,0:16]
                {
                    uint4 a0 = h1b[0][v], a1 = h1b[1][v];
                    unsigned int uu[8] = {a0.x,a0.y,a0.z,a0.w,a1.x,a1.y,a1.z,a1.w};
                    #pragma unroll
                    for (int i = 0; i < 8; ++i) {
                        float f0 = unlo(uu[i]), f1 = unhi(uu[i]);
                        hop2[2*i] = 0.2f*f0; hop2[2*i+1] = 0.2f*f1;
                        #pragma unroll
                        for (int o = 0; o < 16; ++o)
                            y16[o] += mw[o*48 + 2*i]*f0 + mw[o*48 + 2*i+1]*f1;
                    }
                }
                // own hop1: fold mw[:,16:32]
                {
                    uint4 a0 = p1b[0][v], a1 = p1b[1][v];
                    unsigned int uu[8] = {a0.x,a0.y,a0.z,a0.w,a1.x,a1.y,a1.z,a1.w};
                    #pragma unroll
                    for (int i = 0; i < 8; ++i) {
                        float f0 = unlo(uu[i]), f1 = unhi(uu[i]);
                        #pragma unroll
                        for (int o = 0; o < 16; ++o)
                            y16[o] += mw[o*48+16 + 2*i]*f0 + mw[o*48+16 + 2*i+1]*f1;
                    }
                }
                // gather hop2 from hop1
                int base = v*13;
                #pragma unroll
                for (int j = 0; j < 13; ++j) {
                    int nb = adji[base+j];
                    float w = 0.8f*adjw[base+j];
                    uint4 b0 = p1b[0][nb], b1 = p1b[1][nb];
                    unsigned int uu[8] = {b0.x,b0.y,b0.z,b0.w,b1.x,b1.y,b1.z,b1.w};
                    #pragma unroll
                    for (int i = 0; i < 8; ++i) { hop2[2*i] += w*unlo(uu[i]); hop2[2*i+1] += w*unhi(uu[i]); }
                }
                // fold mw[:,32:48] + relu
                #pragma unroll
                for (int o = 0; o < 16; ++o) {
                    float a = y16[o];
                    #pragma unroll
                    for (int c = 0; c < 16; ++c) a += mw[o*48+32+c]*hop2[c];
                    y16[o] = a > 0.f ? a : 0.f;
                }
                // r16 = relu(rw1@y16 + rb1) ; scalar RMW, channel-major (full-line waves)
                float r16[16];
                #pragma unroll
                for (int o = 0; o < 16; ++o) {
                    float a = rb1[o];
                    #pragma unroll
                    for (int i = 0; i < 16; ++i) a += rw1[o*16+i]*y16[i];
                    r16[o] = a > 0.f ? a : 0.f;
                }
                size_t pbase = ((size_t)(b*NG + g)*16)*NN + v;
                if (t == t0) {
                    #pragma unroll
                    for (int o = 0; o < 16; ++o) part[pbase + (size_t)o*NN] = r16[o];
                } else {
                    #pragma unroll
                    for (int o = 0; o < 16; ++o) part[pbase + (size_t)o*NN] += r16[o];
                }
            }
        }
        __syncthreads();   // C/D reads h1b/p1b; next-t A/B overwrite them
    }
}

// ---------------- reduce1: sum over 32 g (coalesced in v), scale 1/162 ----------------
__global__ __launch_bounds__(256) void reduce1_kernel(const float* __restrict__ part,
                                                      float* __restrict__ s16buf)
{
    int idx = blockIdx.x*256 + threadIdx.x;     // over (b*16+c)*NN+v
    if (idx >= BB*16*NN) return;
    int v = idx % NN;
    int rest = idx / NN;
    int c = rest & 15;
    int b = rest >> 4;
    float s = 0.f;
    #pragma unroll
    for (int g = 0; g < NG; ++g)
        s += part[((size_t)(b*NG + g)*16 + c)*NN + v];
    s16buf[idx] = s * (1.0f/TLEN);
}

// ---------------- reduce2: out = rw2 @ s16 + rb2 ----------------
__global__ __launch_bounds__(256) void reduce2_kernel(const float* __restrict__ s16buf,
                                                      const float* __restrict__ rw2,
                                                      const float* __restrict__ rb2,
                                                      float* __restrict__ out)
{
    int idx = blockIdx.x*256 + threadIdx.x;     // over b*NN+v
    if (idx >= BB*NN) return;
    int v = idx % NN;
    int b = idx / NN;
    float s16[16];
    #pragma unroll
    for (int c = 0; c < 16; ++c)
        s16[c] = s16buf[((size_t)b*16 + c)*NN + v];
    #pragma unroll
    for (int o = 0; o < TOUTC; ++o) {
        float a = rb2[o];
        #pragma unroll
        for (int c = 0; c < 16; ++c) a += rw2[o*16+c]*s16[c];
        out[(b*TOUTC + o)*NN + v] = a;
    }
}

extern "C" void kernel_launch(void* const* d_in, const int* in_sizes, int n_in,
                              void* d_out, int out_size, void* d_ws, size_t ws_size,
                              hipStream_t stream)
{
    const float* x   = (const float*)d_in[0];
    const float* pw  = (const float*)d_in[1];
    const float* pb  = (const float*)d_in[2];
    const float* tw2 = (const float*)d_in[3];
    const float* tb2 = (const float*)d_in[4];
    const float* tw3 = (const float*)d_in[5];
    const float* tb3 = (const float*)d_in[6];
    const float* tw6 = (const float*)d_in[7];
    const float* tb6 = (const float*)d_in[8];
    const float* tw7 = (const float*)d_in[9];
    const float* tb7 = (const float*)d_in[10];
    const float* e1  = (const float*)d_in[11];
    const float* e2  = (const float*)d_in[12];
    const float* gw1 = (const float*)d_in[13];
    const float* gb1 = (const float*)d_in[14];
    const float* gw2 = (const float*)d_in[15];
    const float* gb2 = (const float*)d_in[16];
    const float* mw  = (const float*)d_in[17];
    const float* mb  = (const float*)d_in[18];
    const float* rw1 = (const float*)d_in[19];
    const float* rb1 = (const float*)d_in[20];
    const float* rw2 = (const float*)d_in[21];
    const float* rb2 = (const float*)d_in[22];
    float* ws  = (float*)d_ws;
    float* out = (float*)d_out;

    prep_kernel<<<(NN + 255)/256, 256, 0, stream>>>(e1,e2,gw1,gb1,gw2,gb2,pw,pb,
                                                    tw2,tb2,tw3,tb3,tw6,tb6,tw7,tb7, ws);
    graph_kernel<<<NN, 256, 0, stream>>>(ws + OFF_M1, ws + OFF_M2,
                                         ws + OFF_ADJW, (int*)ws + OFF_ADJI);
    main_kernel<<<BB*NG, NTH, 0, stream>>>(x, ws + OFF_EW, ws + OFF_EB,
                                           ws + OFF_ADJW, (const int*)ws + OFF_ADJI,
                                           ws + OFF_PART, mw, mb, rw1, rb1);
    reduce1_kernel<<<(BB*16*NN + 255)/256, 256, 0, stream>>>(ws + OFF_PART, ws + OFF_S16);
    reduce2_kernel<<<(BB*NN + 255)/256, 256, 0, stream>>>(ws + OFF_S16, rw2, rb2, out);
}

// Round 14
// 506.747 us; speedup vs baseline: 1.2908x; 1.2908x over previous
//
#include <hip/hip_runtime.h>

#define BB 8
#define TIN 168
#define NN 1500
#define TOUTC 24
#define TLEN 162
#define NG 32
#define NTH 768
#define SN 2
#define TOPKK 12

// workspace offsets (in 4-byte elements)
#define OFF_M1   0
#define OFF_M2   24000
#define OFF_EW   48000
#define OFF_EB   48112
#define OFF_ADJW 48128
#define OFF_ADJI 67628
#define OFF_S16  87136      // 8*16*1500 = 192000 floats, [b][c][v]
#define OFF_PART 279136     // 8*32*16*1500 floats, [bg][c][v] channel-major
// total ws = 6,423,136 floats = 25.7 MB

__device__ __forceinline__ unsigned short f2bf(float f) {
    unsigned int u = __float_as_uint(f);
    unsigned int r = (u + 0x7fffu + ((u >> 16) & 1u)) >> 16;
    return (unsigned short)r;
}
__device__ __forceinline__ unsigned int pack2(float lo, float hi) {
    return (unsigned int)f2bf(lo) | ((unsigned int)f2bf(hi) << 16);
}
__device__ __forceinline__ float unlo(unsigned int u) { return __uint_as_float(u << 16); }
__device__ __forceinline__ float unhi(unsigned int u) { return __uint_as_float(u & 0xffff0000u); }

// ---------------- prep: m1/m2 embeddings + effective inception taps ----------------
__global__ __launch_bounds__(256) void prep_kernel(
    const float* __restrict__ e1, const float* __restrict__ e2,
    const float* __restrict__ gw1, const float* __restrict__ gb1,
    const float* __restrict__ gw2, const float* __restrict__ gb2,
    const float* __restrict__ pw, const float* __restrict__ pb,
    const float* __restrict__ tw2, const float* __restrict__ tb2,
    const float* __restrict__ tw3, const float* __restrict__ tb3,
    const float* __restrict__ tw6, const float* __restrict__ tb6,
    const float* __restrict__ tw7, const float* __restrict__ tb7,
    float* __restrict__ ws)
{
    int n = blockIdx.x * blockDim.x + threadIdx.x;
    if (n < NN) {
        float a1[16], a2[16];
        #pragma unroll
        for (int o = 0; o < 16; ++o) { a1[o] = gb1[o]; a2[o] = gb2[o]; }
        #pragma unroll
        for (int i = 0; i < 16; ++i) {
            float u = e1[n*16+i], v = e2[n*16+i];
            #pragma unroll
            for (int o = 0; o < 16; ++o) {
                a1[o] += u * gw1[i*16+o];
                a2[o] += v * gw2[i*16+o];
            }
        }
        #pragma unroll
        for (int o = 0; o < 16; ++o) {
            ws[OFF_M1 + n*16+o] = tanhf(1.5f*a1[o]);
            ws[OFF_M2 + n*16+o] = tanhf(1.5f*a2[o]);
        }
    }
    if (blockIdx.x == 0 && threadIdx.x < 16) {
        int c = threadIdx.x;
        int br = c >> 2, oc = c & 3;
        const float* tw; const float* tb; int k;
        if (br == 0)      { tw = tw2; tb = tb2; k = 2; }
        else if (br == 1) { tw = tw3; tb = tb3; k = 3; }
        else if (br == 2) { tw = tw6; tb = tb6; k = 6; }
        else              { tw = tw7; tb = tb7; k = 7; }
        for (int d = 0; d < 7; ++d) ws[OFF_EW + c*7 + d] = 0.f;
        float ebv = tb[oc];
        for (int j = 0; j < k; ++j) {
            float s = 0.f, sb = 0.f;
            for (int ic = 0; ic < 16; ++ic) {
                float w = tw[(oc*16+ic)*k + j];
                s  += w * pw[ic];
                sb += w * pb[ic];
            }
            ws[OFF_EW + c*7 + (7-k+j)] = s;
            ebv += sb;
        }
        ws[OFF_EB + c] = ebv;
    }
}

// ---------------- graph: scores in registers + shuffle-argmax top-12 ----------------
__global__ __launch_bounds__(256) void graph_kernel(
    const float* __restrict__ m1, const float* __restrict__ m2,
    float* __restrict__ adjw, int* __restrict__ adji)
{
    int v = blockIdx.x;
    int tid = threadIdx.x;
    __shared__ float wv4[4];
    __shared__ int   wi4[4];
    __shared__ int   bcast_i;
    __shared__ float m1v[16], m2v[16];
    if (tid < 16) { m1v[tid] = m1[v*16+tid]; m2v[tid] = m2[v*16+tid]; }
    __syncthreads();
    const float4* m1f = (const float4*)m1;
    const float4* m2f = (const float4*)m2;
    float sreg[6];
    #pragma unroll
    for (int u = 0; u < 6; ++u) {
        int j = tid + 256*u;
        float a = -1.f;
        if (j < NN) {
            float d = 0.f;
            #pragma unroll
            for (int q = 0; q < 4; ++q) {
                float4 r2 = m2f[j*4+q];
                float4 r1 = m1f[j*4+q];
                d += m1v[4*q+0]*r2.x - m2v[4*q+0]*r1.x;
                d += m1v[4*q+1]*r2.y - m2v[4*q+1]*r1.y;
                d += m1v[4*q+2]*r2.z - m2v[4*q+2]*r1.z;
                d += m1v[4*q+3]*r2.w - m2v[4*q+3]*r1.w;
            }
            float t = tanhf(1.5f*d);
            a = t > 0.f ? t : 0.f;
        }
        sreg[u] = a;
    }
    float lb = -1.f; int li = NN;
    #pragma unroll
    for (int u = 0; u < 6; ++u) {
        int j = tid + 256*u;
        if (j < NN && sreg[u] > lb) { lb = sreg[u]; li = j; }
    }
    const int wid = tid >> 6;
    for (int it = 0; it < TOPKK; ++it) {
        float bv = lb; int bi = li;
        #pragma unroll
        for (int off = 32; off > 0; off >>= 1) {
            float ov = __shfl_down(bv, off);
            int   oi = __shfl_down(bi, off);
            if (ov > bv || (ov == bv && oi < bi)) { bv = ov; bi = oi; }
        }
        if ((tid & 63) == 0) { wv4[wid] = bv; wi4[wid] = bi; }
        __syncthreads();
        if (tid == 0) {
            #pragma unroll
            for (int w = 1; w < 4; ++w) {
                float ov = wv4[w]; int oi = wi4[w];
                if (ov > bv || (ov == bv && oi < bi)) { bv = ov; bi = oi; }
            }
            adjw[v*13+it] = bv;
            adji[v*13+it] = bi;
            bcast_i = bi;
        }
        __syncthreads();
        int win = bcast_i;
        if (li == win) {
            #pragma unroll
            for (int u = 0; u < 6; ++u)
                if (tid + 256*u == win) sreg[u] = -1.f;
            lb = -1.f; li = NN;
            #pragma unroll
            for (int u = 0; u < 6; ++u) {
                int j = tid + 256*u;
                if (j < NN && sreg[u] > lb) { lb = sreg[u]; li = j; }
            }
        }
    }
    if (tid == 0) {
        float s = 1.f;
        #pragma unroll
        for (int it = 0; it < TOPKK; ++it) s += adjw[v*13+it];
        float inv = 1.f/s;
        #pragma unroll
        for (int it = 0; it < TOPKK; ++it) adjw[v*13+it] *= inv;
        adji[v*13+12] = v;
        adjw[v*13+12] = inv;   // normalized self-loop
    }
}

// ---------------- main: pipelined 2-barrier t-loop (double-buffered h1) ----------------
// R9-proven inner code at NTH=768 (VGPR=84 allocation fits the live set; R13 showed
// 1024 thr -> 64-reg target -> spill storm). With 1 block/CU every __syncthreads
// serializes the CU; double-buffering h1 lets phase A(t+1) merge into phase C/D(t),
// cutting barriers from 3/t to 2/t. Numerics identical to R9.
__global__ __launch_bounds__(NTH, 3) void main_kernel(
    const float* __restrict__ x,
    const float* __restrict__ ew, const float* __restrict__ eb,
    const float* __restrict__ adjw, const int* __restrict__ adji,
    float* __restrict__ part,
    const float* __restrict__ mw, const float* __restrict__ mb,
    const float* __restrict__ rw1, const float* __restrict__ rb1)
{
    // SoA by row: row r holds channels 8r..8r+7 (uint4 = 8 bf16), contiguous in v.
    __shared__ uint4 h1b[2][2][NN];   // 2 x 48000 B : h1 bf16, double-buffered
    __shared__ uint4 p1b[2][NN];      //     48000 B : hop1 bf16

    const int tid = threadIdx.x;
    const int b = blockIdx.x >> 5;
    const int g = blockIdx.x & 31;
    const int t0 = (g*TLEN) >> 5;
    const int t1 = ((g+1)*TLEN) >> 5;

    // ---- prologue: phase A for t0 into buffer 0 ----
    #pragma unroll 1
    for (int s = 0; s < SN; ++s) {
        int v = tid + NTH*s;
        if (v < NN) {
            float xv[7];
            #pragma unroll
            for (int d = 0; d < 7; ++d) xv[d] = x[(b*TIN + t0 + d)*NN + v];
            float h[16];
            #pragma unroll
            for (int c = 0; c < 16; ++c) {
                float a = eb[c];
                #pragma unroll
                for (int d = 0; d < 7; ++d) a += ew[c*7+d]*xv[d];
                h[c] = a > 0.f ? a : 0.f;
            }
            h1b[0][0][v] = make_uint4(pack2(h[0],h[1]), pack2(h[2],h[3]), pack2(h[4],h[5]), pack2(h[6],h[7]));
            h1b[0][1][v] = make_uint4(pack2(h[8],h[9]), pack2(h[10],h[11]), pack2(h[12],h[13]), pack2(h[14],h[15]));
        }
    }
    __syncthreads();

    for (int t = t0; t < t1; ++t) {
        const int cur = (t - t0) & 1;
        const int nxt = cur ^ 1;
        // ---- Phase B: hop1 = 0.2*h1own + 0.8*A@h1 -> p1b (from h1b[cur]) ----
        #pragma unroll 1
        for (int s = 0; s < SN; ++s) {
            int v = tid + NTH*s;
            if (v < NN) {
                float hp[16];
                {
                    uint4 a0 = h1b[cur][0][v], a1 = h1b[cur][1][v];
                    unsigned int uu[8] = {a0.x,a0.y,a0.z,a0.w,a1.x,a1.y,a1.z,a1.w};
                    #pragma unroll
                    for (int i = 0; i < 8; ++i) { hp[2*i] = 0.2f*unlo(uu[i]); hp[2*i+1] = 0.2f*unhi(uu[i]); }
                }
                int base = v*13;
                #pragma unroll
                for (int j = 0; j < 13; ++j) {
                    int nb = adji[base+j];
                    float w = 0.8f*adjw[base+j];
                    uint4 b0 = h1b[cur][0][nb], b1 = h1b[cur][1][nb];
                    unsigned int uu[8] = {b0.x,b0.y,b0.z,b0.w,b1.x,b1.y,b1.z,b1.w};
                    #pragma unroll
                    for (int i = 0; i < 8; ++i) { hp[2*i] += w*unlo(uu[i]); hp[2*i+1] += w*unhi(uu[i]); }
                }
                p1b[0][v] = make_uint4(pack2(hp[0],hp[1]), pack2(hp[2],hp[3]), pack2(hp[4],hp[5]), pack2(hp[6],hp[7]));
                p1b[1][v] = make_uint4(pack2(hp[8],hp[9]), pack2(hp[10],hp[11]), pack2(hp[12],hp[13]), pack2(hp[14],hp[15]));
            }
        }
        __syncthreads();
        // ---- Merged phase: A(t+1) -> h1b[nxt], then C/D(t) from h1b[cur] + p1b ----
        if (t + 1 < t1) {
            #pragma unroll 1
            for (int s = 0; s < SN; ++s) {
                int v = tid + NTH*s;
                if (v < NN) {
                    float xv[7];
                    #pragma unroll
                    for (int d = 0; d < 7; ++d) xv[d] = x[(b*TIN + (t+1) + d)*NN + v];
                    float h[16];
                    #pragma unroll
                    for (int c = 0; c < 16; ++c) {
                        float a = eb[c];
                        #pragma unroll
                        for (int d = 0; d < 7; ++d) a += ew[c*7+d]*xv[d];
                        h[c] = a > 0.f ? a : 0.f;
                    }
                    h1b[nxt][0][v] = make_uint4(pack2(h[0],h[1]), pack2(h[2],h[3]), pack2(h[4],h[5]), pack2(h[6],h[7]));
                    h1b[nxt][1][v] = make_uint4(pack2(h[8],h[9]), pack2(h[10],h[11]), pack2(h[12],h[13]), pack2(h[14],h[15]));
                }
            }
        }
        #pragma unroll 1
        for (int s = 0; s < SN; ++s) {
            int v = tid + NTH*s;
            if (v < NN) {
                float y16[16];
                #pragma unroll
                for (int o = 0; o < 16; ++o) y16[o] = mb[o];
                float hop2[16];
                // own h1: hop2 base + fold mw[:,0:16]
                {
                    uint4 a0 = h1b[cur][0][v], a1 = h1b[cur][1][v];
                    unsigned int uu[8] = {a0.x,a0.y,a0.z,a0.w,a1.x,a1.y,a1.z,a1.w};
                    #pragma unroll
                    for (int i = 0; i < 8; ++i) {
                        float f0 = unlo(uu[i]), f1 = unhi(uu[i]);
                        hop2[2*i] = 0.2f*f0; hop2[2*i+1] = 0.2f*f1;
                        #pragma unroll
                        for (int o = 0; o < 16; ++o)
                            y16[o] += mw[o*48 + 2*i]*f0 + mw[o*48 + 2*i+1]*f1;
                    }
                }
                // own hop1: fold mw[:,16:32]
                {
                    uint4 a0 = p1b[0][v], a1 = p1b[1][v];
                    unsigned int uu[8] = {a0.x,a0.y,a0.z,a0.w,a1.x,a1.y,a1.z,a1.w};
                    #pragma unroll
                    for (int i = 0; i < 8; ++i) {
                        float f0 = unlo(uu[i]), f1 = unhi(uu[i]);
                        #pragma unroll
                        for (int o = 0; o < 16; ++o)
                            y16[o] += mw[o*48+16 + 2*i]*f0 + mw[o*48+16 + 2*i+1]*f1;
                    }
                }
                // gather hop2 from hop1
                int base = v*13;
                #pragma unroll
                for (int j = 0; j < 13; ++j) {
                    int nb = adji[base+j];
                    float w = 0.8f*adjw[base+j];
                    uint4 b0 = p1b[0][nb], b1 = p1b[1][nb];
                    unsigned int uu[8] = {b0.x,b0.y,b0.z,b0.w,b1.x,b1.y,b1.z,b1.w};
                    #pragma unroll
                    for (int i = 0; i < 8; ++i) { hop2[2*i] += w*unlo(uu[i]); hop2[2*i+1] += w*unhi(uu[i]); }
                }
                // fold mw[:,32:48] + relu
                #pragma unroll
                for (int o = 0; o < 16; ++o) {
                    float a = y16[o];
                    #pragma unroll
                    for (int c = 0; c < 16; ++c) a += mw[o*48+32+c]*hop2[c];
                    y16[o] = a > 0.f ? a : 0.f;
                }
                // r16 = relu(rw1@y16 + rb1) ; scalar RMW, channel-major (full-line waves)
                float r16[16];
                #pragma unroll
                for (int o = 0; o < 16; ++o) {
                    float a = rb1[o];
                    #pragma unroll
                    for (int i = 0; i < 16; ++i) a += rw1[o*16+i]*y16[i];
                    r16[o] = a > 0.f ? a : 0.f;
                }
                size_t pbase = ((size_t)(b*NG + g)*16)*NN + v;
                if (t == t0) {
                    #pragma unroll
                    for (int o = 0; o < 16; ++o) part[pbase + (size_t)o*NN] = r16[o];
                } else {
                    #pragma unroll
                    for (int o = 0; o < 16; ++o) part[pbase + (size_t)o*NN] += r16[o];
                }
            }
        }
        __syncthreads();   // p1b overwritten next B; h1b[nxt] read next B
    }
}

// ---------------- reduce1: sum over 32 g (coalesced in v), scale 1/162 ----------------
__global__ __launch_bounds__(256) void reduce1_kernel(const float* __restrict__ part,
                                                      float* __restrict__ s16buf)
{
    int idx = blockIdx.x*256 + threadIdx.x;     // over (b*16+c)*NN+v
    if (idx >= BB*16*NN) return;
    int v = idx % NN;
    int rest = idx / NN;
    int c = rest & 15;
    int b = rest >> 4;
    float s = 0.f;
    #pragma unroll
    for (int g = 0; g < NG; ++g)
        s += part[((size_t)(b*NG + g)*16 + c)*NN + v];
    s16buf[idx] = s * (1.0f/TLEN);
}

// ---------------- reduce2: out = rw2 @ s16 + rb2 ----------------
__global__ __launch_bounds__(256) void reduce2_kernel(const float* __restrict__ s16buf,
                                                      const float* __restrict__ rw2,
                                                      const float* __restrict__ rb2,
                                                      float* __restrict__ out)
{
    int idx = blockIdx.x*256 + threadIdx.x;     // over b*NN+v
    if (idx >= BB*NN) return;
    int v = idx % NN;
    int b = idx / NN;
    float s16[16];
    #pragma unroll
    for (int c = 0; c < 16; ++c)
        s16[c] = s16buf[((size_t)b*16 + c)*NN + v];
    #pragma unroll
    for (int o = 0; o < TOUTC; ++o) {
        float a = rb2[o];
        #pragma unroll
        for (int c = 0; c < 16; ++c) a += rw2[o*16+c]*s16[c];
        out[(b*TOUTC + o)*NN + v] = a;
    }
}

extern "C" void kernel_launch(void* const* d_in, const int* in_sizes, int n_in,
                              void* d_out, int out_size, void* d_ws, size_t ws_size,
                              hipStream_t stream)
{
    const float* x   = (const float*)d_in[0];
    const float* pw  = (const float*)d_in[1];
    const float* pb  = (const float*)d_in[2];
    const float* tw2 = (const float*)d_in[3];
    const float* tb2 = (const float*)d_in[4];
    const float* tw3 = (const float*)d_in[5];
    const float* tb3 = (const float*)d_in[6];
    const float* tw6 = (const float*)d_in[7];
    const float* tb6 = (const float*)d_in[8];
    const float* tw7 = (const float*)d_in[9];
    const float* tb7 = (const float*)d_in[10];
    const float* e1  = (const float*)d_in[11];
    const float* e2  = (const float*)d_in[12];
    const float* gw1 = (const float*)d_in[13];
    const float* gb1 = (const float*)d_in[14];
    const float* gw2 = (const float*)d_in[15];
    const float* gb2 = (const float*)d_in[16];
    const float* mw  = (const float*)d_in[17];
    const float* mb  = (const float*)d_in[18];
    const float* rw1 = (const float*)d_in[19];
    const float* rb1 = (const float*)d_in[20];
    const float* rw2 = (const float*)d_in[21];
    const float* rb2 = (const float*)d_in[22];
    float* ws  = (float*)d_ws;
    float* out = (float*)d_out;

    prep_kernel<<<(NN + 255)/256, 256, 0, stream>>>(e1,e2,gw1,gb1,gw2,gb2,pw,pb,
                                                    tw2,tb2,tw3,tb3,tw6,tb6,tw7,tb7, ws);
    graph_kernel<<<NN, 256, 0, stream>>>(ws + OFF_M1, ws + OFF_M2,
                                         ws + OFF_ADJW, (int*)ws + OFF_ADJI);
    main_kernel<<<BB*NG, NTH, 0, stream>>>(x, ws + OFF_EW, ws + OFF_EB,
                                           ws + OFF_ADJW, (const int*)ws + OFF_ADJI,
                                           ws + OFF_PART, mw, mb, rw1, rb1);
    reduce1_kernel<<<(BB*16*NN + 255)/256, 256, 0, stream>>>(ws + OFF_PART, ws + OFF_S16);
    reduce2_kernel<<<(BB*NN + 255)/256, 256, 0, stream>>>(ws + OFF_S16, rw2, rb2, out);
}

// Round 15
// 334.737 us; speedup vs baseline: 1.9541x; 1.5139x over previous
//
#include <hip/hip_runtime.h>

#define BB 8
#define TIN 168
#define NN 1500
#define TOUTC 24
#define TLEN 162
#define NG 32
#define NTH 768
#define SN 2
#define TOPKK 12
#define NTILE 94   // ceil(1504/16)

// workspace offsets (in 4-byte elements)
#define OFF_M1   0
#define OFF_M2   24000
#define OFF_EW   48000
#define OFF_EB   48112
#define OFF_ADJW 48128
#define OFF_ADJI 67628
#define OFF_FR   87128      // 6 frag planes x 512 ushorts = 1536 floats
#define OFF_S16  88664      // 8*1500*16 = 192000 floats
#define OFF_PART 280664     // 8*32*1500*16 = 6,144,000 floats ([bg][v][16])
// total ws = 6,424,664 floats = 25.7 MB

typedef __attribute__((ext_vector_type(8))) short short8;
typedef __attribute__((ext_vector_type(4))) float v4f;

__device__ __forceinline__ unsigned short f2bf(float f) {
    unsigned int u = __float_as_uint(f);
    unsigned int r = (u + 0x7fffu + ((u >> 16) & 1u)) >> 16;
    return (unsigned short)r;
}
__device__ __forceinline__ unsigned int pack2(float lo, float hi) {
    return (unsigned int)f2bf(lo) | ((unsigned int)f2bf(hi) << 16);
}
__device__ __forceinline__ float unlo(unsigned int u) { return __uint_as_float(u << 16); }
__device__ __forceinline__ float unhi(unsigned int u) { return __uint_as_float(u & 0xffff0000u); }
__device__ __forceinline__ float bf2f(unsigned short s) { return __uint_as_float(((unsigned int)s) << 16); }

__device__ __forceinline__ short8 as_s8(uint4 u) { union { uint4 a; short8 b; } c; c.a = u; return c.b; }
__device__ __forceinline__ uint4 zf_u4(v4f f)    { union { v4f a; uint4 b; } c; c.a = f; return c.b; }

// ---------------- prep: embeddings + eff. taps + MFMA weight fragments ----------------
__global__ __launch_bounds__(256) void prep_kernel(
    const float* __restrict__ e1, const float* __restrict__ e2,
    const float* __restrict__ gw1, const float* __restrict__ gb1,
    const float* __restrict__ gw2, const float* __restrict__ gb2,
    const float* __restrict__ pw, const float* __restrict__ pb,
    const float* __restrict__ tw2, const float* __restrict__ tb2,
    const float* __restrict__ tw3, const float* __restrict__ tb3,
    const float* __restrict__ tw6, const float* __restrict__ tb6,
    const float* __restrict__ tw7, const float* __restrict__ tb7,
    const float* __restrict__ mw, const float* __restrict__ rw1,
    float* __restrict__ ws)
{
    int n = blockIdx.x * blockDim.x + threadIdx.x;
    if (n < NN) {
        float a1[16], a2[16];
        #pragma unroll
        for (int o = 0; o < 16; ++o) { a1[o] = gb1[o]; a2[o] = gb2[o]; }
        #pragma unroll
        for (int i = 0; i < 16; ++i) {
            float u = e1[n*16+i], v = e2[n*16+i];
            #pragma unroll
            for (int o = 0; o < 16; ++o) {
                a1[o] += u * gw1[i*16+o];
                a2[o] += v * gw2[i*16+o];
            }
        }
        #pragma unroll
        for (int o = 0; o < 16; ++o) {
            ws[OFF_M1 + n*16+o] = tanhf(1.5f*a1[o]);
            ws[OFF_M2 + n*16+o] = tanhf(1.5f*a2[o]);
        }
    }
    if (blockIdx.x == 0 && threadIdx.x < 16) {
        int c = threadIdx.x;
        int br = c >> 2, oc = c & 3;
        const float* tw; const float* tb; int k;
        if (br == 0)      { tw = tw2; tb = tb2; k = 2; }
        else if (br == 1) { tw = tw3; tb = tb3; k = 3; }
        else if (br == 2) { tw = tw6; tb = tb6; k = 6; }
        else              { tw = tw7; tb = tb7; k = 7; }
        for (int d = 0; d < 7; ++d) ws[OFF_EW + c*7 + d] = 0.f;
        float ebv = tb[oc];
        for (int j = 0; j < k; ++j) {
            float s = 0.f, sb = 0.f;
            for (int ic = 0; ic < 16; ++ic) {
                float w = tw[(oc*16+ic)*k + j];
                s  += w * pw[ic];
                sb += w * pb[ic];
            }
            ws[OFF_EW + c*7 + (7-k+j)] = s;
            ebv += sb;
        }
        ws[OFF_EB + c] = ebv;
    }
    // MFMA weight fragments (hi/lo bf16 split): A[m=lane&15][k=(lane>>4)*8+j]
    // mat0 = [W1|U] (K=32): W1=M1+0.2(M2+M3), U=0.8M2+0.16M3  (M* = mw 16x16 blocks)
    // mat1 = [V2|0]: V2=0.64M3 ;  mat2 = [rw1|0]
    if (blockIdx.x == 1 && threadIdx.x < 64) {
        int lane = threadIdx.x;
        int m = lane & 15, q = lane >> 4;
        unsigned short* frw = (unsigned short*)(ws + OFF_FR);
        for (int mat = 0; mat < 3; ++mat) {
            for (int j = 0; j < 8; ++j) {
                int k = q*8 + j;
                float s;
                if (mat == 0) s = (k < 16) ? mw[m*48+k] + 0.2f*(mw[m*48+16+k] + mw[m*48+32+k])
                                           : 0.8f*mw[m*48+16+(k-16)] + 0.16f*mw[m*48+32+(k-16)];
                else if (mat == 1) s = (k < 16) ? 0.64f*mw[m*48+32+k] : 0.f;
                else               s = (k < 16) ? rw1[m*16+k] : 0.f;
                unsigned short hi = f2bf(s);
                unsigned short lo = f2bf(s - bf2f(hi));
                frw[(mat*2+0)*512 + lane*8 + j] = hi;
                frw[(mat*2+1)*512 + lane*8 + j] = lo;
            }
        }
    }
}

// ---------------- graph: scores in registers + shuffle-argmax top-12 ----------------
__global__ __launch_bounds__(256) void graph_kernel(
    const float* __restrict__ m1, const float* __restrict__ m2,
    float* __restrict__ adjw, int* __restrict__ adji)
{
    int v = blockIdx.x;
    int tid = threadIdx.x;
    __shared__ float wv4[4];
    __shared__ int   wi4[4];
    __shared__ int   bcast_i;
    __shared__ float m1v[16], m2v[16];
    if (tid < 16) { m1v[tid] = m1[v*16+tid]; m2v[tid] = m2[v*16+tid]; }
    __syncthreads();
    const float4* m1f = (const float4*)m1;
    const float4* m2f = (const float4*)m2;
    float sreg[6];
    #pragma unroll
    for (int u = 0; u < 6; ++u) {
        int j = tid + 256*u;
        float a = -1.f;
        if (j < NN) {
            float d = 0.f;
            #pragma unroll
            for (int q = 0; q < 4; ++q) {
                float4 r2 = m2f[j*4+q];
                float4 r1 = m1f[j*4+q];
                d += m1v[4*q+0]*r2.x - m2v[4*q+0]*r1.x;
                d += m1v[4*q+1]*r2.y - m2v[4*q+1]*r1.y;
                d += m1v[4*q+2]*r2.z - m2v[4*q+2]*r1.z;
                d += m1v[4*q+3]*r2.w - m2v[4*q+3]*r1.w;
            }
            float t = tanhf(1.5f*d);
            a = t > 0.f ? t : 0.f;
        }
        sreg[u] = a;
    }
    float lb = -1.f; int li = NN;
    #pragma unroll
    for (int u = 0; u < 6; ++u) {
        int j = tid + 256*u;
        if (j < NN && sreg[u] > lb) { lb = sreg[u]; li = j; }
    }
    const int wid = tid >> 6;
    for (int it = 0; it < TOPKK; ++it) {
        float bv = lb; int bi = li;
        #pragma unroll
        for (int off = 32; off > 0; off >>= 1) {
            float ov = __shfl_down(bv, off);
            int   oi = __shfl_down(bi, off);
            if (ov > bv || (ov == bv && oi < bi)) { bv = ov; bi = oi; }
        }
        if ((tid & 63) == 0) { wv4[wid] = bv; wi4[wid] = bi; }
        __syncthreads();
        if (tid == 0) {
            #pragma unroll
            for (int w = 1; w < 4; ++w) {
                float ov = wv4[w]; int oi = wi4[w];
                if (ov > bv || (ov == bv && oi < bi)) { bv = ov; bi = oi; }
            }
            adjw[v*13+it] = bv;
            adji[v*13+it] = bi;
            bcast_i = bi;
        }
        __syncthreads();
        int win = bcast_i;
        if (li == win) {
            #pragma unroll
            for (int u = 0; u < 6; ++u)
                if (tid + 256*u == win) sreg[u] = -1.f;
            lb = -1.f; li = NN;
            #pragma unroll
            for (int u = 0; u < 6; ++u) {
                int j = tid + 256*u;
                if (j < NN && sreg[u] > lb) { lb = sreg[u]; li = j; }
            }
        }
    }
    if (tid == 0) {
        float s = 1.f;
        #pragma unroll
        for (int it = 0; it < TOPKK; ++it) s += adjw[v*13+it];
        float inv = 1.f/s;
        #pragma unroll
        for (int it = 0; it < TOPKK; ++it) adjw[v*13+it] *= inv;
        adji[v*13+12] = v;
        adjw[v*13+12] = inv;   // normalized self-loop
    }
}

__device__ __forceinline__ short8 ldfrag(const unsigned short* fr, int plane, int lane) {
    const uint4* p = (const uint4*)(fr + plane*512);
    return as_s8(p[lane]);
}

// ---------------- main ----------------
// Per t: A: h1 -> feat[0:32] (bf16). B1: u1 = A@h1 gather -> feat[32:64] (bf16).
// B2 (MFMA): z = [W1|U]@[h1;u1] -> feat[0:64] (fp32, in-place); p = V2@u1 -> qb (bf16).
// D1: y16 = relu(mb + z + gather(p)) -> feat[0:32] (bf16), zero feat[32:64].
// D2 (MFMA): r16 = relu(rw1@y16 + rb1) -> contiguous float4 part-RMW (1 KB/wave-inst).
// Weight frags hi/lo-split: weight bf16 rounding ~eliminated. s-loops unroll 1 (R9 spill fix).
__global__ __launch_bounds__(NTH, 3) void main_kernel(
    const float* __restrict__ x,
    const float* __restrict__ ew, const float* __restrict__ eb,
    const float* __restrict__ adjw, const int* __restrict__ adji,
    const unsigned short* __restrict__ fr,
    float* __restrict__ part,
    const float* __restrict__ mb, const float* __restrict__ rb1)
{
    __shared__ uint4 feat4[1504*4];  // 96256 B: per node 64 B
    __shared__ uint4 qb4[1504*2];    // 48128 B: per node 32 B (p bf16)

    const int tid = threadIdx.x;
    const int lane = tid & 63;
    const int wid = tid >> 6;
    const int b = blockIdx.x >> 5;
    const int g = blockIdx.x & 31;
    const int t0 = (g*TLEN) >> 5;
    const int t1 = ((g+1)*TLEN) >> 5;
    float* partBG = part + (size_t)(b*NG + g)*NN*16;

    for (int t = t0; t < t1; ++t) {
        // ---- Phase A: 7-tap conv -> h1 bf16 ----
        #pragma unroll 1
        for (int s = 0; s < SN; ++s) {
            int v = tid + NTH*s;
            if (v < NN) {
                float xv[7];
                #pragma unroll
                for (int d = 0; d < 7; ++d) xv[d] = x[(b*TIN + t + d)*NN + v];
                float h[16];
                #pragma unroll
                for (int c = 0; c < 16; ++c) {
                    float a = eb[c];
                    #pragma unroll
                    for (int d = 0; d < 7; ++d) a += ew[c*7+d]*xv[d];
                    h[c] = a > 0.f ? a : 0.f;
                }
                feat4[v*4+0] = make_uint4(pack2(h[0],h[1]), pack2(h[2],h[3]), pack2(h[4],h[5]), pack2(h[6],h[7]));
                feat4[v*4+1] = make_uint4(pack2(h[8],h[9]), pack2(h[10],h[11]), pack2(h[12],h[13]), pack2(h[14],h[15]));
            }
        }
        __syncthreads();
        // ---- Phase B1: u1 = A@h1 (raw weights, incl self-loop) -> feat[32:64] bf16 ----
        #pragma unroll 1
        for (int s = 0; s < SN; ++s) {
            int v = tid + NTH*s;
            if (v < NN) {
                float u1[16];
                #pragma unroll
                for (int c = 0; c < 16; ++c) u1[c] = 0.f;
                int base = v*13;
                #pragma unroll
                for (int j = 0; j < 13; ++j) {
                    int nb = adji[base+j];
                    float w = adjw[base+j];
                    uint4 b0 = feat4[nb*4+0], b1 = feat4[nb*4+1];
                    unsigned int uu[8] = {b0.x,b0.y,b0.z,b0.w,b1.x,b1.y,b1.z,b1.w};
                    #pragma unroll
                    for (int i = 0; i < 8; ++i) { u1[2*i] += w*unlo(uu[i]); u1[2*i+1] += w*unhi(uu[i]); }
                }
                feat4[v*4+2] = make_uint4(pack2(u1[0],u1[1]), pack2(u1[2],u1[3]), pack2(u1[4],u1[5]), pack2(u1[6],u1[7]));
                feat4[v*4+3] = make_uint4(pack2(u1[8],u1[9]), pack2(u1[10],u1[11]), pack2(u1[12],u1[13]), pack2(u1[14],u1[15]));
            }
        }
        __syncthreads();
        // ---- Phase B2 (MFMA): z (fp32, in-place over feat) and p (bf16 -> qb) ----
        {
            short8 a1h = ldfrag(fr, 0, lane), a1l = ldfrag(fr, 1, lane);
            short8 a2h = ldfrag(fr, 2, lane), a2l = ldfrag(fr, 3, lane);
            const int n0 = lane & 15, q = lane >> 4;
            #pragma unroll 1
            for (int T = wid; T < NTILE; T += 12) {
                int n = T*16 + n0;
                short8 bf  = as_s8(feat4[n*4 + q]);
                short8 b2f = as_s8(feat4[n*4 + 2 + (q & 1)]);
                v4f z = {0.f,0.f,0.f,0.f}, p = {0.f,0.f,0.f,0.f};
                z = __builtin_amdgcn_mfma_f32_16x16x32_bf16(a1h, bf, z, 0, 0, 0);
                z = __builtin_amdgcn_mfma_f32_16x16x32_bf16(a1l, bf, z, 0, 0, 0);
                p = __builtin_amdgcn_mfma_f32_16x16x32_bf16(a2h, b2f, p, 0, 0, 0);
                p = __builtin_amdgcn_mfma_f32_16x16x32_bf16(a2l, b2f, p, 0, 0, 0);
                feat4[n*4 + q] = zf_u4(z);   // z fp32: ch q*4..q*4+3
                ushort4 pp;
                pp.x = f2bf(p[0]); pp.y = f2bf(p[1]); pp.z = f2bf(p[2]); pp.w = f2bf(p[3]);
                ((ushort4*)qb4)[n*4 + q] = pp;
            }
        }
        __syncthreads();
        // ---- Phase D1: y16 = relu(mb + z + gather(p)) -> feat[0:32] bf16; zero feat[32:64] ----
        #pragma unroll 1
        for (int s = 0; s < SN; ++s) {
            int v = tid + NTH*s;
            if (v < NN) {
                float y[16];
                #pragma unroll
                for (int qq = 0; qq < 4; ++qq) {
                    uint4 zz = feat4[v*4+qq];
                    y[qq*4+0] = mb[qq*4+0] + __uint_as_float(zz.x);
                    y[qq*4+1] = mb[qq*4+1] + __uint_as_float(zz.y);
                    y[qq*4+2] = mb[qq*4+2] + __uint_as_float(zz.z);
                    y[qq*4+3] = mb[qq*4+3] + __uint_as_float(zz.w);
                }
                int base = v*13;
                #pragma unroll
                for (int j = 0; j < 13; ++j) {
                    int nb = adji[base+j];
                    float w = adjw[base+j];
                    uint4 p0 = qb4[nb*2+0], p1 = qb4[nb*2+1];
                    unsigned int uu[8] = {p0.x,p0.y,p0.z,p0.w,p1.x,p1.y,p1.z,p1.w};
                    #pragma unroll
                    for (int i = 0; i < 8; ++i) { y[2*i] += w*unlo(uu[i]); y[2*i+1] += w*unhi(uu[i]); }
                }
                #pragma unroll
                for (int o = 0; o < 16; ++o) y[o] = y[o] > 0.f ? y[o] : 0.f;
                feat4[v*4+0] = make_uint4(pack2(y[0],y[1]), pack2(y[2],y[3]), pack2(y[4],y[5]), pack2(y[6],y[7]));
                feat4[v*4+1] = make_uint4(pack2(y[8],y[9]), pack2(y[10],y[11]), pack2(y[12],y[13]), pack2(y[14],y[15]));
                feat4[v*4+2] = make_uint4(0,0,0,0);   // padded K-quads must be finite (0)
                feat4[v*4+3] = make_uint4(0,0,0,0);
            }
        }
        __syncthreads();
        // ---- Phase D2 (MFMA): r16 = relu(rw1@y16 + rb1); part RMW (float4) ----
        {
            short8 a3h = ldfrag(fr, 4, lane), a3l = ldfrag(fr, 5, lane);
            const int n0 = lane & 15, q = lane >> 4;
            float rb[4];
            #pragma unroll
            for (int r = 0; r < 4; ++r) rb[r] = rb1[q*4+r];
            #pragma unroll 1
            for (int T = wid; T < NTILE; T += 12) {
                int n = T*16 + n0;
                short8 bf = as_s8(feat4[n*4 + q]);
                v4f acc = {0.f,0.f,0.f,0.f};
                acc = __builtin_amdgcn_mfma_f32_16x16x32_bf16(a3h, bf, acc, 0, 0, 0);
                acc = __builtin_amdgcn_mfma_f32_16x16x32_bf16(a3l, bf, acc, 0, 0, 0);
                if (n < NN) {
                    float r0 = acc[0]+rb[0], r1 = acc[1]+rb[1], r2 = acc[2]+rb[2], r3 = acc[3]+rb[3];
                    r0 = r0 > 0.f ? r0 : 0.f;  r1 = r1 > 0.f ? r1 : 0.f;
                    r2 = r2 > 0.f ? r2 : 0.f;  r3 = r3 > 0.f ? r3 : 0.f;
                    float4* pp = (float4*)(partBG + (size_t)n*16 + q*4);
                    if (t == t0) {
                        *pp = make_float4(r0, r1, r2, r3);
                    } else {
                        float4 o = *pp;
                        *pp = make_float4(o.x+r0, o.y+r1, o.z+r2, o.w+r3);
                    }
                }
            }
        }
        __syncthreads();   // D2 reads feat; next-t A overwrites feat
    }
}

// ---------------- reduce1: sum over 32 g (coalesced), scale 1/162 ----------------
__global__ __launch_bounds__(256) void reduce1_kernel(const float* __restrict__ part,
                                                      float* __restrict__ s16buf)
{
    int idx = blockIdx.x*256 + threadIdx.x;     // over (b*NN+v)*16+c
    if (idx >= BB*NN*16) return;
    int c = idx & 15;
    int rest = idx >> 4;
    int v = rest % NN;
    int b = rest / NN;
    float s = 0.f;
    #pragma unroll
    for (int g = 0; g < NG; ++g)
        s += part[((size_t)(b*NG + g)*NN + v)*16 + c];
    s16buf[idx] = s * (1.0f/TLEN);
}

// ---------------- reduce2: out = rw2 @ s16 + rb2 ----------------
__global__ __launch_bounds__(256) void reduce2_kernel(const float* __restrict__ s16buf,
                                                      const float* __restrict__ rw2,
                                                      const float* __restrict__ rb2,
                                                      float* __restrict__ out)
{
    int idx = blockIdx.x*256 + threadIdx.x;     // over b*NN+v
    if (idx >= BB*NN) return;
    int v = idx % NN;
    int b = idx / NN;
    const float4* sp = (const float4*)(s16buf + (size_t)idx*16);
    float4 s0 = sp[0], s1 = sp[1], s2 = sp[2], s3 = sp[3];
    float s16[16] = {s0.x,s0.y,s0.z,s0.w, s1.x,s1.y,s1.z,s1.w,
                     s2.x,s2.y,s2.z,s2.w, s3.x,s3.y,s3.z,s3.w};
    #pragma unroll
    for (int o = 0; o < TOUTC; ++o) {
        float a = rb2[o];
        #pragma unroll
        for (int c = 0; c < 16; ++c) a += rw2[o*16+c]*s16[c];
        out[(b*TOUTC + o)*NN + v] = a;
    }
}

extern "C" void kernel_launch(void* const* d_in, const int* in_sizes, int n_in,
                              void* d_out, int out_size, void* d_ws, size_t ws_size,
                              hipStream_t stream)
{
    const float* x   = (const float*)d_in[0];
    const float* pw  = (const float*)d_in[1];
    const float* pb  = (const float*)d_in[2];
    const float* tw2 = (const float*)d_in[3];
    const float* tb2 = (const float*)d_in[4];
    const float* tw3 = (const float*)d_in[5];
    const float* tb3 = (const float*)d_in[6];
    const float* tw6 = (const float*)d_in[7];
    const float* tb6 = (const float*)d_in[8];
    const float* tw7 = (const float*)d_in[9];
    const float* tb7 = (const float*)d_in[10];
    const float* e1  = (const float*)d_in[11];
    const float* e2  = (const float*)d_in[12];
    const float* gw1 = (const float*)d_in[13];
    const float* gb1 = (const float*)d_in[14];
    const float* gw2 = (const float*)d_in[15];
    const float* gb2 = (const float*)d_in[16];
    const float* mw  = (const float*)d_in[17];
    const float* mb  = (const float*)d_in[18];
    const float* rw1 = (const float*)d_in[19];
    const float* rb1 = (const float*)d_in[20];
    const float* rw2 = (const float*)d_in[21];
    const float* rb2 = (const float*)d_in[22];
    float* ws  = (float*)d_ws;
    float* out = (float*)d_out;

    prep_kernel<<<(NN + 255)/256, 256, 0, stream>>>(e1,e2,gw1,gb1,gw2,gb2,pw,pb,
                                                    tw2,tb2,tw3,tb3,tw6,tb6,tw7,tb7,
                                                    mw, rw1, ws);
    graph_kernel<<<NN, 256, 0, stream>>>(ws + OFF_M1, ws + OFF_M2,
                                         ws + OFF_ADJW, (int*)ws + OFF_ADJI);
    main_kernel<<<BB*NG, NTH, 0, stream>>>(x, ws + OFF_EW, ws + OFF_EB,
                                           ws + OFF_ADJW, (const int*)ws + OFF_ADJI,
                                           (const unsigned short*)(ws + OFF_FR),
                                           ws + OFF_PART, mb, rb1);
    reduce1_kernel<<<(BB*NN*16 + 255)/256, 256, 0, stream>>>(ws + OFF_PART, ws + OFF_S16);
    reduce2_kernel<<<(BB*NN + 255)/256, 256, 0, stream>>>(ws + OFF_S16, rw2, rb2, out);
}

// Round 16
// 299.710 us; speedup vs baseline: 2.1825x; 1.1169x over previous
//
#include <hip/hip_runtime.h>

#define BB 8
#define TIN 168
#define NN 1500
#define TOUTC 24
#define TLEN 162
#define NG 32
#define NTH 768
#define SN 2
#define TOPKK 12
#define NTILE 94   // ceil(1504/16)
#define NPAD 1504

// workspace offsets (in 4-byte elements)
#define OFF_M1   0
#define OFF_M2   24000
#define OFF_EW   48000
#define OFF_EB   48112
#define OFF_ADJW 48128
#define OFF_ADJI 67628
#define OFF_FR   87128      // 6 frag planes x 512 ushorts = 1536 floats
#define OFF_S16  88664      // 8*1500*16 = 192000 floats
#define OFF_PART 280664     // 8*32*1500*16 = 6,144,000 floats ([bg][v][16])
// total ws = 6,424,664 floats = 25.7 MB

typedef __attribute__((ext_vector_type(8))) short short8;
typedef __attribute__((ext_vector_type(4))) float v4f;

__device__ __forceinline__ unsigned short f2bf(float f) {
    unsigned int u = __float_as_uint(f);
    unsigned int r = (u + 0x7fffu + ((u >> 16) & 1u)) >> 16;
    return (unsigned short)r;
}
__device__ __forceinline__ unsigned int pack2(float lo, float hi) {
    return (unsigned int)f2bf(lo) | ((unsigned int)f2bf(hi) << 16);
}
__device__ __forceinline__ float unlo(unsigned int u) { return __uint_as_float(u << 16); }
__device__ __forceinline__ float unhi(unsigned int u) { return __uint_as_float(u & 0xffff0000u); }
__device__ __forceinline__ float bf2f(unsigned short s) { return __uint_as_float(((unsigned int)s) << 16); }

__device__ __forceinline__ short8 as_s8(uint4 u) { union { uint4 a; short8 b; } c; c.a = u; return c.b; }
__device__ __forceinline__ uint4 zf_u4(v4f f)    { union { v4f a; uint4 b; } c; c.a = f; return c.b; }

// ---------------- prep: embeddings + eff. taps + MFMA weight fragments ----------------
__global__ __launch_bounds__(256) void prep_kernel(
    const float* __restrict__ e1, const float* __restrict__ e2,
    const float* __restrict__ gw1, const float* __restrict__ gb1,
    const float* __restrict__ gw2, const float* __restrict__ gb2,
    const float* __restrict__ pw, const float* __restrict__ pb,
    const float* __restrict__ tw2, const float* __restrict__ tb2,
    const float* __restrict__ tw3, const float* __restrict__ tb3,
    const float* __restrict__ tw6, const float* __restrict__ tb6,
    const float* __restrict__ tw7, const float* __restrict__ tb7,
    const float* __restrict__ mw, const float* __restrict__ rw1,
    float* __restrict__ ws)
{
    int n = blockIdx.x * blockDim.x + threadIdx.x;
    if (n < NN) {
        float a1[16], a2[16];
        #pragma unroll
        for (int o = 0; o < 16; ++o) { a1[o] = gb1[o]; a2[o] = gb2[o]; }
        #pragma unroll
        for (int i = 0; i < 16; ++i) {
            float u = e1[n*16+i], v = e2[n*16+i];
            #pragma unroll
            for (int o = 0; o < 16; ++o) {
                a1[o] += u * gw1[i*16+o];
                a2[o] += v * gw2[i*16+o];
            }
        }
        #pragma unroll
        for (int o = 0; o < 16; ++o) {
            ws[OFF_M1 + n*16+o] = tanhf(1.5f*a1[o]);
            ws[OFF_M2 + n*16+o] = tanhf(1.5f*a2[o]);
        }
    }
    if (blockIdx.x == 0 && threadIdx.x < 16) {
        int c = threadIdx.x;
        int br = c >> 2, oc = c & 3;
        const float* tw; const float* tb; int k;
        if (br == 0)      { tw = tw2; tb = tb2; k = 2; }
        else if (br == 1) { tw = tw3; tb = tb3; k = 3; }
        else if (br == 2) { tw = tw6; tb = tb6; k = 6; }
        else              { tw = tw7; tb = tb7; k = 7; }
        for (int d = 0; d < 7; ++d) ws[OFF_EW + c*7 + d] = 0.f;
        float ebv = tb[oc];
        for (int j = 0; j < k; ++j) {
            float s = 0.f, sb = 0.f;
            for (int ic = 0; ic < 16; ++ic) {
                float w = tw[(oc*16+ic)*k + j];
                s  += w * pw[ic];
                sb += w * pb[ic];
            }
            ws[OFF_EW + c*7 + (7-k+j)] = s;
            ebv += sb;
        }
        ws[OFF_EB + c] = ebv;
    }
    // MFMA weight fragments (hi/lo bf16 split): A[m=lane&15][k=(lane>>4)*8+j]
    // mat0 = [W1|U] (K=32): W1=M1+0.2(M2+M3), U=0.8M2+0.16M3  (M* = mw 16x16 blocks)
    // mat1 = [V2|0]: V2=0.64M3 ;  mat2 = [rw1|0]
    if (blockIdx.x == 1 && threadIdx.x < 64) {
        int lane = threadIdx.x;
        int m = lane & 15, q = lane >> 4;
        unsigned short* frw = (unsigned short*)(ws + OFF_FR);
        for (int mat = 0; mat < 3; ++mat) {
            for (int j = 0; j < 8; ++j) {
                int k = q*8 + j;
                float s;
                if (mat == 0) s = (k < 16) ? mw[m*48+k] + 0.2f*(mw[m*48+16+k] + mw[m*48+32+k])
                                           : 0.8f*mw[m*48+16+(k-16)] + 0.16f*mw[m*48+32+(k-16)];
                else if (mat == 1) s = (k < 16) ? 0.64f*mw[m*48+32+k] : 0.f;
                else               s = (k < 16) ? rw1[m*16+k] : 0.f;
                unsigned short hi = f2bf(s);
                unsigned short lo = f2bf(s - bf2f(hi));
                frw[(mat*2+0)*512 + lane*8 + j] = hi;
                frw[(mat*2+1)*512 + lane*8 + j] = lo;
            }
        }
    }
}

// ---------------- graph: scores in registers + shuffle-argmax top-12 ----------------
__global__ __launch_bounds__(256) void graph_kernel(
    const float* __restrict__ m1, const float* __restrict__ m2,
    float* __restrict__ adjw, int* __restrict__ adji)
{
    int v = blockIdx.x;
    int tid = threadIdx.x;
    __shared__ float wv4[4];
    __shared__ int   wi4[4];
    __shared__ int   bcast_i;
    __shared__ float m1v[16], m2v[16];
    if (tid < 16) { m1v[tid] = m1[v*16+tid]; m2v[tid] = m2[v*16+tid]; }
    __syncthreads();
    const float4* m1f = (const float4*)m1;
    const float4* m2f = (const float4*)m2;
    float sreg[6];
    #pragma unroll
    for (int u = 0; u < 6; ++u) {
        int j = tid + 256*u;
        float a = -1.f;
        if (j < NN) {
            float d = 0.f;
            #pragma unroll
            for (int q = 0; q < 4; ++q) {
                float4 r2 = m2f[j*4+q];
                float4 r1 = m1f[j*4+q];
                d += m1v[4*q+0]*r2.x - m2v[4*q+0]*r1.x;
                d += m1v[4*q+1]*r2.y - m2v[4*q+1]*r1.y;
                d += m1v[4*q+2]*r2.z - m2v[4*q+2]*r1.z;
                d += m1v[4*q+3]*r2.w - m2v[4*q+3]*r1.w;
            }
            float t = tanhf(1.5f*d);
            a = t > 0.f ? t : 0.f;
        }
        sreg[u] = a;
    }
    float lb = -1.f; int li = NN;
    #pragma unroll
    for (int u = 0; u < 6; ++u) {
        int j = tid + 256*u;
        if (j < NN && sreg[u] > lb) { lb = sreg[u]; li = j; }
    }
    const int wid = tid >> 6;
    for (int it = 0; it < TOPKK; ++it) {
        float bv = lb; int bi = li;
        #pragma unroll
        for (int off = 32; off > 0; off >>= 1) {
            float ov = __shfl_down(bv, off);
            int   oi = __shfl_down(bi, off);
            if (ov > bv || (ov == bv && oi < bi)) { bv = ov; bi = oi; }
        }
        if ((tid & 63) == 0) { wv4[wid] = bv; wi4[wid] = bi; }
        __syncthreads();
        if (tid == 0) {
            #pragma unroll
            for (int w = 1; w < 4; ++w) {
                float ov = wv4[w]; int oi = wi4[w];
                if (ov > bv || (ov == bv && oi < bi)) { bv = ov; bi = oi; }
            }
            adjw[v*13+it] = bv;
            adji[v*13+it] = bi;
            bcast_i = bi;
        }
        __syncthreads();
        int win = bcast_i;
        if (li == win) {
            #pragma unroll
            for (int u = 0; u < 6; ++u)
                if (tid + 256*u == win) sreg[u] = -1.f;
            lb = -1.f; li = NN;
            #pragma unroll
            for (int u = 0; u < 6; ++u) {
                int j = tid + 256*u;
                if (j < NN && sreg[u] > lb) { lb = sreg[u]; li = j; }
            }
        }
    }
    if (tid == 0) {
        float s = 1.f;
        #pragma unroll
        for (int it = 0; it < TOPKK; ++it) s += adjw[v*13+it];
        float inv = 1.f/s;
        #pragma unroll
        for (int it = 0; it < TOPKK; ++it) adjw[v*13+it] *= inv;
        adji[v*13+12] = v;
        adjw[v*13+12] = inv;   // normalized self-loop
    }
}

__device__ __forceinline__ short8 ldfrag(const unsigned short* fr, int plane, int lane) {
    const uint4* p = (const uint4*)(fr + plane*512);
    return as_s8(p[lane]);
}

// ---------------- main ----------------
// PLANE-MAJOR LDS (R16): feat[plane][node], node stride 16 B. Group = node mod 8
// -> every fixed-plane access (scalar v-consecutive AND MFMA n-consecutive) spreads
// across all 8 bank-groups. R15's per-node-64B layout put quarter-waves on 2 of 8
// groups (8-way conflict, 4.2e7 cycles). Math identical to R15.
// Planes: 0-1 = h1 bf16 (ch0-7, ch8-15) -> z fp32 (ch0-3..) -> y16 bf16 ;
//         2-3 = u1 bf16 -> z fp32 -> zero. qp2[2][NPAD]: p bf16 (ch0-7, ch8-15).
__global__ __launch_bounds__(NTH, 3) void main_kernel(
    const float* __restrict__ x,
    const float* __restrict__ ew, const float* __restrict__ eb,
    const float* __restrict__ adjw, const int* __restrict__ adji,
    const unsigned short* __restrict__ fr,
    float* __restrict__ part,
    const float* __restrict__ mb, const float* __restrict__ rb1)
{
    __shared__ uint4 feat[4][NPAD];  // 96256 B
    __shared__ uint4 qp2[2][NPAD];   // 48128 B

    const int tid = threadIdx.x;
    const int lane = tid & 63;
    const int wid = tid >> 6;
    const int b = blockIdx.x >> 5;
    const int g = blockIdx.x & 31;
    const int t0 = (g*TLEN) >> 5;
    const int t1 = ((g+1)*TLEN) >> 5;
    float* partBG = part + (size_t)(b*NG + g)*NN*16;

    for (int t = t0; t < t1; ++t) {
        // ---- Phase A: 7-tap conv -> h1 bf16 (planes 0,1) ----
        #pragma unroll 1
        for (int s = 0; s < SN; ++s) {
            int v = tid + NTH*s;
            if (v < NN) {
                float xv[7];
                #pragma unroll
                for (int d = 0; d < 7; ++d) xv[d] = x[(b*TIN + t + d)*NN + v];
                float h[16];
                #pragma unroll
                for (int c = 0; c < 16; ++c) {
                    float a = eb[c];
                    #pragma unroll
                    for (int d = 0; d < 7; ++d) a += ew[c*7+d]*xv[d];
                    h[c] = a > 0.f ? a : 0.f;
                }
                feat[0][v] = make_uint4(pack2(h[0],h[1]), pack2(h[2],h[3]), pack2(h[4],h[5]), pack2(h[6],h[7]));
                feat[1][v] = make_uint4(pack2(h[8],h[9]), pack2(h[10],h[11]), pack2(h[12],h[13]), pack2(h[14],h[15]));
            }
        }
        __syncthreads();
        // ---- Phase B1: u1 = A@h1 (raw weights, incl self-loop) -> planes 2,3 bf16 ----
        #pragma unroll 1
        for (int s = 0; s < SN; ++s) {
            int v = tid + NTH*s;
            if (v < NN) {
                float u1[16];
                #pragma unroll
                for (int c = 0; c < 16; ++c) u1[c] = 0.f;
                int base = v*13;
                #pragma unroll
                for (int j = 0; j < 13; ++j) {
                    int nb = adji[base+j];
                    float w = adjw[base+j];
                    uint4 b0 = feat[0][nb], b1 = feat[1][nb];
                    unsigned int uu[8] = {b0.x,b0.y,b0.z,b0.w,b1.x,b1.y,b1.z,b1.w};
                    #pragma unroll
                    for (int i = 0; i < 8; ++i) { u1[2*i] += w*unlo(uu[i]); u1[2*i+1] += w*unhi(uu[i]); }
                }
                feat[2][v] = make_uint4(pack2(u1[0],u1[1]), pack2(u1[2],u1[3]), pack2(u1[4],u1[5]), pack2(u1[6],u1[7]));
                feat[3][v] = make_uint4(pack2(u1[8],u1[9]), pack2(u1[10],u1[11]), pack2(u1[12],u1[13]), pack2(u1[14],u1[15]));
            }
        }
        __syncthreads();
        // ---- Phase B2 (MFMA): z = [W1|U]@[h1;u1] (fp32, in-place over feat planes);
        //      p = V2@u1 -> qp2 bf16 (lane writes its ushort4 half-slot) ----
        {
            short8 a1h = ldfrag(fr, 0, lane), a1l = ldfrag(fr, 1, lane);
            short8 a2h = ldfrag(fr, 2, lane), a2l = ldfrag(fr, 3, lane);
            const int n0 = lane & 15, q = lane >> 4;
            ushort4* qpH = (ushort4*)qp2;     // 2 planes x NPAD nodes x 2 halves
            #pragma unroll 1
            for (int T = wid; T < NTILE; T += 12) {
                int n = T*16 + n0;
                short8 bf  = as_s8(feat[q][n]);          // k-quad q of [h1;u1]
                short8 b2f = as_s8(feat[2 + (q & 1)][n]); // u1 planes (upper-K weights are 0)
                v4f z = {0.f,0.f,0.f,0.f}, p = {0.f,0.f,0.f,0.f};
                z = __builtin_amdgcn_mfma_f32_16x16x32_bf16(a1h, bf, z, 0, 0, 0);
                z = __builtin_amdgcn_mfma_f32_16x16x32_bf16(a1l, bf, z, 0, 0, 0);
                p = __builtin_amdgcn_mfma_f32_16x16x32_bf16(a2h, b2f, p, 0, 0, 0);
                p = __builtin_amdgcn_mfma_f32_16x16x32_bf16(a2l, b2f, p, 0, 0, 0);
                feat[q][n] = zf_u4(z);   // z fp32: ch q*4..q*4+3
                ushort4 pp;
                pp.x = f2bf(p[0]); pp.y = f2bf(p[1]); pp.z = f2bf(p[2]); pp.w = f2bf(p[3]);
                qpH[(q >> 1)*(NPAD*2) + n*2 + (q & 1)] = pp;   // ch 4q..4q+3
            }
        }
        __syncthreads();
        // ---- Phase D1: y16 = relu(mb + z + gather(p)) -> planes 0,1 bf16; zero 2,3 ----
        #pragma unroll 1
        for (int s = 0; s < SN; ++s) {
            int v = tid + NTH*s;
            if (v < NN) {
                float y[16];
                #pragma unroll
                for (int qq = 0; qq < 4; ++qq) {
                    uint4 zz = feat[qq][v];
                    y[qq*4+0] = mb[qq*4+0] + __uint_as_float(zz.x);
                    y[qq*4+1] = mb[qq*4+1] + __uint_as_float(zz.y);
                    y[qq*4+2] = mb[qq*4+2] + __uint_as_float(zz.z);
                    y[qq*4+3] = mb[qq*4+3] + __uint_as_float(zz.w);
                }
                int base = v*13;
                #pragma unroll
                for (int j = 0; j < 13; ++j) {
                    int nb = adji[base+j];
                    float w = adjw[base+j];
                    uint4 p0 = qp2[0][nb], p1 = qp2[1][nb];
                    unsigned int uu[8] = {p0.x,p0.y,p0.z,p0.w,p1.x,p1.y,p1.z,p1.w};
                    #pragma unroll
                    for (int i = 0; i < 8; ++i) { y[2*i] += w*unlo(uu[i]); y[2*i+1] += w*unhi(uu[i]); }
                }
                #pragma unroll
                for (int o = 0; o < 16; ++o) y[o] = y[o] > 0.f ? y[o] : 0.f;
                feat[0][v] = make_uint4(pack2(y[0],y[1]), pack2(y[2],y[3]), pack2(y[4],y[5]), pack2(y[6],y[7]));
                feat[1][v] = make_uint4(pack2(y[8],y[9]), pack2(y[10],y[11]), pack2(y[12],y[13]), pack2(y[14],y[15]));
                feat[2][v] = make_uint4(0,0,0,0);   // padded K-quads must be finite (0)
                feat[3][v] = make_uint4(0,0,0,0);
            }
        }
        __syncthreads();
        // ---- Phase D2 (MFMA): r16 = relu(rw1@y16 + rb1); part RMW (float4) ----
        {
            short8 a3h = ldfrag(fr, 4, lane), a3l = ldfrag(fr, 5, lane);
            const int n0 = lane & 15, q = lane >> 4;
            float rb[4];
            #pragma unroll
            for (int r = 0; r < 4; ++r) rb[r] = rb1[q*4+r];
            #pragma unroll 1
            for (int T = wid; T < NTILE; T += 12) {
                int n = T*16 + n0;
                short8 bf = as_s8(feat[q][n]);
                v4f acc = {0.f,0.f,0.f,0.f};
                acc = __builtin_amdgcn_mfma_f32_16x16x32_bf16(a3h, bf, acc, 0, 0, 0);
                acc = __builtin_amdgcn_mfma_f32_16x16x32_bf16(a3l, bf, acc, 0, 0, 0);
                if (n < NN) {
                    float r0 = acc[0]+rb[0], r1 = acc[1]+rb[1], r2 = acc[2]+rb[2], r3 = acc[3]+rb[3];
                    r0 = r0 > 0.f ? r0 : 0.f;  r1 = r1 > 0.f ? r1 : 0.f;
                    r2 = r2 > 0.f ? r2 : 0.f;  r3 = r3 > 0.f ? r3 : 0.f;
                    float4* pp = (float4*)(partBG + (size_t)n*16 + q*4);
                    if (t == t0) {
                        *pp = make_float4(r0, r1, r2, r3);
                    } else {
                        float4 o = *pp;
                        *pp = make_float4(o.x+r0, o.y+r1, o.z+r2, o.w+r3);
                    }
                }
            }
        }
        __syncthreads();   // D2 reads feat; next-t A overwrites feat
    }
}

// ---------------- reduce1: sum over 32 g (coalesced), scale 1/162 ----------------
__global__ __launch_bounds__(256) void reduce1_kernel(const float* __restrict__ part,
                                                      float* __restrict__ s16buf)
{
    int idx = blockIdx.x*256 + threadIdx.x;     // over (b*NN+v)*16+c
    if (idx >= BB*NN*16) return;
    int c = idx & 15;
    int rest = idx >> 4;
    int v = rest % NN;
    int b = rest / NN;
    float s = 0.f;
    #pragma unroll
    for (int g = 0; g < NG; ++g)
        s += part[((size_t)(b*NG + g)*NN + v)*16 + c];
    s16buf[idx] = s * (1.0f/TLEN);
}

// ---------------- reduce2: out = rw2 @ s16 + rb2 ----------------
__global__ __launch_bounds__(256) void reduce2_kernel(const float* __restrict__ s16buf,
                                                      const float* __restrict__ rw2,
                                                      const float* __restrict__ rb2,
                                                      float* __restrict__ out)
{
    int idx = blockIdx.x*256 + threadIdx.x;     // over b*NN+v
    if (idx >= BB*NN) return;
    int v = idx % NN;
    int b = idx / NN;
    const float4* sp = (const float4*)(s16buf + (size_t)idx*16);
    float4 s0 = sp[0], s1 = sp[1], s2 = sp[2], s3 = sp[3];
    float s16[16] = {s0.x,s0.y,s0.z,s0.w, s1.x,s1.y,s1.z,s1.w,
                     s2.x,s2.y,s2.z,s2.w, s3.x,s3.y,s3.z,s3.w};
    #pragma unroll
    for (int o = 0; o < TOUTC; ++o) {
        float a = rb2[o];
        #pragma unroll
        for (int c = 0; c < 16; ++c) a += rw2[o*16+c]*s16[c];
        out[(b*TOUTC + o)*NN + v] = a;
    }
}

extern "C" void kernel_launch(void* const* d_in, const int* in_sizes, int n_in,
                              void* d_out, int out_size, void* d_ws, size_t ws_size,
                              hipStream_t stream)
{
    const float* x   = (const float*)d_in[0];
    const float* pw  = (const float*)d_in[1];
    const float* pb  = (const float*)d_in[2];
    const float* tw2 = (const float*)d_in[3];
    const float* tb2 = (const float*)d_in[4];
    const float* tw3 = (const float*)d_in[5];
    const float* tb3 = (const float*)d_in[6];
    const float* tw6 = (const float*)d_in[7];
    const float* tb6 = (const float*)d_in[8];
    const float* tw7 = (const float*)d_in[9];
    const float* tb7 = (const float*)d_in[10];
    const float* e1  = (const float*)d_in[11];
    const float* e2  = (const float*)d_in[12];
    const float* gw1 = (const float*)d_in[13];
    const float* gb1 = (const float*)d_in[14];
    const float* gw2 = (const float*)d_in[15];
    const float* gb2 = (const float*)d_in[16];
    const float* mw  = (const float*)d_in[17];
    const float* mb  = (const float*)d_in[18];
    const float* rw1 = (const float*)d_in[19];
    const float* rb1 = (const float*)d_in[20];
    const float* rw2 = (const float*)d_in[21];
    const float* rb2 = (const float*)d_in[22];
    float* ws  = (float*)d_ws;
    float* out = (float*)d_out;

    prep_kernel<<<(NN + 255)/256, 256, 0, stream>>>(e1,e2,gw1,gb1,gw2,gb2,pw,pb,
                                                    tw2,tb2,tw3,tb3,tw6,tb6,tw7,tb7,
                                                    mw, rw1, ws);
    graph_kernel<<<NN, 256, 0, stream>>>(ws + OFF_M1, ws + OFF_M2,
                                         ws + OFF_ADJW, (int*)ws + OFF_ADJI);
    main_kernel<<<BB*NG, NTH, 0, stream>>>(x, ws + OFF_EW, ws + OFF_EB,
                                           ws + OFF_ADJW, (const int*)ws + OFF_ADJI,
                                           (const unsigned short*)(ws + OFF_FR),
                                           ws + OFF_PART, mb, rb1);
    reduce1_kernel<<<(BB*NN*16 + 255)/256, 256, 0, stream>>>(ws + OFF_PART, ws + OFF_S16);
    reduce2_kernel<<<(BB*NN + 255)/256, 256, 0, stream>>>(ws + OFF_S16, rw2, rb2, out);
}

// Round 17
// 298.982 us; speedup vs baseline: 2.1878x; 1.0024x over previous
//
#include <hip/hip_runtime.h>

#define BB 8
#define TIN 168
#define NN 1500
#define TOUTC 24
#define TLEN 162
#define NG 32
#define NTH 768
#define SN 2
#define TOPKK 12
#define NTILE 94   // ceil(1504/16)
#define NPAD 1504

// workspace offsets (in 4-byte elements)
#define OFF_M1   0
#define OFF_M2   24000
#define OFF_M1T  48000
#define OFF_M2T  72000
#define OFF_EW   96000
#define OFF_EB   96112
#define OFF_ADJW 96128
#define OFF_ADJI 115628
#define OFF_FR   135128     // 6 frag planes x 512 ushorts = 1536 floats
#define OFF_S16  136664     // 8*1500*16 = 192000 floats
#define OFF_PART 328664     // 8*32*1500*16 = 6,144,000 floats ([bg][v][16])
// total ws = 6,472,664 floats = 25.9 MB

typedef __attribute__((ext_vector_type(8))) short short8;
typedef __attribute__((ext_vector_type(4))) float v4f;

__device__ __forceinline__ unsigned short f2bf(float f) {
    unsigned int u = __float_as_uint(f);
    unsigned int r = (u + 0x7fffu + ((u >> 16) & 1u)) >> 16;
    return (unsigned short)r;
}
__device__ __forceinline__ unsigned int pack2(float lo, float hi) {
    return (unsigned int)f2bf(lo) | ((unsigned int)f2bf(hi) << 16);
}
__device__ __forceinline__ float unlo(unsigned int u) { return __uint_as_float(u << 16); }
__device__ __forceinline__ float unhi(unsigned int u) { return __uint_as_float(u & 0xffff0000u); }
__device__ __forceinline__ float bf2f(unsigned short s) { return __uint_as_float(((unsigned int)s) << 16); }

__device__ __forceinline__ short8 as_s8(uint4 u) { union { uint4 a; short8 b; } c; c.a = u; return c.b; }

// ---------------- prep: embeddings (+transposed copies) + eff. taps + MFMA weight frags ----------------
__global__ __launch_bounds__(256) void prep_kernel(
    const float* __restrict__ e1, const float* __restrict__ e2,
    const float* __restrict__ gw1, const float* __restrict__ gb1,
    const float* __restrict__ gw2, const float* __restrict__ gb2,
    const float* __restrict__ pw, const float* __restrict__ pb,
    const float* __restrict__ tw2, const float* __restrict__ tb2,
    const float* __restrict__ tw3, const float* __restrict__ tb3,
    const float* __restrict__ tw6, const float* __restrict__ tb6,
    const float* __restrict__ tw7, const float* __restrict__ tb7,
    const float* __restrict__ mw, const float* __restrict__ rw1,
    float* __restrict__ ws)
{
    int n = blockIdx.x * blockDim.x + threadIdx.x;
    if (n < NN) {
        float a1[16], a2[16];
        #pragma unroll
        for (int o = 0; o < 16; ++o) { a1[o] = gb1[o]; a2[o] = gb2[o]; }
        #pragma unroll
        for (int i = 0; i < 16; ++i) {
            float u = e1[n*16+i], v = e2[n*16+i];
            #pragma unroll
            for (int o = 0; o < 16; ++o) {
                a1[o] += u * gw1[i*16+o];
                a2[o] += v * gw2[i*16+o];
            }
        }
        #pragma unroll
        for (int o = 0; o < 16; ++o) {
            float t1v = tanhf(1.5f*a1[o]);
            float t2v = tanhf(1.5f*a2[o]);
            ws[OFF_M1 + n*16+o] = t1v;
            ws[OFF_M2 + n*16+o] = t2v;
            ws[OFF_M1T + o*NN + n] = t1v;   // transposed: coalesced graph reads
            ws[OFF_M2T + o*NN + n] = t2v;
        }
    }
    if (blockIdx.x == 0 && threadIdx.x < 16) {
        int c = threadIdx.x;
        int br = c >> 2, oc = c & 3;
        const float* tw; const float* tb; int k;
        if (br == 0)      { tw = tw2; tb = tb2; k = 2; }
        else if (br == 1) { tw = tw3; tb = tb3; k = 3; }
        else if (br == 2) { tw = tw6; tb = tb6; k = 6; }
        else              { tw = tw7; tb = tb7; k = 7; }
        for (int d = 0; d < 7; ++d) ws[OFF_EW + c*7 + d] = 0.f;
        float ebv = tb[oc];
        for (int j = 0; j < k; ++j) {
            float s = 0.f, sb = 0.f;
            for (int ic = 0; ic < 16; ++ic) {
                float w = tw[(oc*16+ic)*k + j];
                s  += w * pw[ic];
                sb += w * pb[ic];
            }
            ws[OFF_EW + c*7 + (7-k+j)] = s;
            ebv += sb;
        }
        ws[OFF_EB + c] = ebv;
    }
    // MFMA weight fragments (hi/lo bf16 split): A[m=lane&15][k=(lane>>4)*8+j]
    // mat0 = [W1|U] (K=32): W1=M1+0.2(M2+M3), U=0.8M2+0.16M3  (M* = mw 16x16 blocks)
    // mat1 = [V2|0]: V2=0.64M3 ;  mat2 = [rw1|0]
    if (blockIdx.x == 1 && threadIdx.x < 64) {
        int lane = threadIdx.x;
        int m = lane & 15, q = lane >> 4;
        unsigned short* frw = (unsigned short*)(ws + OFF_FR);
        for (int mat = 0; mat < 3; ++mat) {
            for (int j = 0; j < 8; ++j) {
                int k = q*8 + j;
                float s;
                if (mat == 0) s = (k < 16) ? mw[m*48+k] + 0.2f*(mw[m*48+16+k] + mw[m*48+32+k])
                                           : 0.8f*mw[m*48+16+(k-16)] + 0.16f*mw[m*48+32+(k-16)];
                else if (mat == 1) s = (k < 16) ? 0.64f*mw[m*48+32+k] : 0.f;
                else               s = (k < 16) ? rw1[m*16+k] : 0.f;
                unsigned short hi = f2bf(s);
                unsigned short lo = f2bf(s - bf2f(hi));
                frw[(mat*2+0)*512 + lane*8 + j] = hi;
                frw[(mat*2+1)*512 + lane*8 + j] = lo;
            }
        }
    }
}

// ---------------- graph: coalesced transposed score loads + shuffle-argmax top-12 ----------------
__global__ __launch_bounds__(256) void graph_kernel(
    const float* __restrict__ m1, const float* __restrict__ m2,
    const float* __restrict__ m1T, const float* __restrict__ m2T,
    float* __restrict__ adjw, int* __restrict__ adji)
{
    int v = blockIdx.x;
    int tid = threadIdx.x;
    __shared__ float wv4[4];
    __shared__ int   wi4[4];
    __shared__ int   bcast_i;
    __shared__ float m1v[16], m2v[16];
    if (tid < 16) { m1v[tid] = m1[v*16+tid]; m2v[tid] = m2[v*16+tid]; }
    __syncthreads();
    float sreg[6];
    #pragma unroll
    for (int u = 0; u < 6; ++u) {
        int j = tid + 256*u;
        float a = -1.f;
        if (j < NN) {
            float d = 0.f;
            #pragma unroll
            for (int i = 0; i < 16; ++i)
                d += m1v[i]*m2T[i*NN+j] - m2v[i]*m1T[i*NN+j];   // lane-consecutive j: full lines
            float t = tanhf(1.5f*d);
            a = t > 0.f ? t : 0.f;
        }
        sreg[u] = a;
    }
    float lb = -1.f; int li = NN;
    #pragma unroll
    for (int u = 0; u < 6; ++u) {
        int j = tid + 256*u;
        if (j < NN && sreg[u] > lb) { lb = sreg[u]; li = j; }
    }
    const int wid = tid >> 6;
    for (int it = 0; it < TOPKK; ++it) {
        float bv = lb; int bi = li;
        #pragma unroll
        for (int off = 32; off > 0; off >>= 1) {
            float ov = __shfl_down(bv, off);
            int   oi = __shfl_down(bi, off);
            if (ov > bv || (ov == bv && oi < bi)) { bv = ov; bi = oi; }
        }
        if ((tid & 63) == 0) { wv4[wid] = bv; wi4[wid] = bi; }
        __syncthreads();
        if (tid == 0) {
            #pragma unroll
            for (int w = 1; w < 4; ++w) {
                float ov = wv4[w]; int oi = wi4[w];
                if (ov > bv || (ov == bv && oi < bi)) { bv = ov; bi = oi; }
            }
            adjw[v*13+it] = bv;
            adji[v*13+it] = bi;
            bcast_i = bi;
        }
        __syncthreads();
        int win = bcast_i;
        if (li == win) {
            #pragma unroll
            for (int u = 0; u < 6; ++u)
                if (tid + 256*u == win) sreg[u] = -1.f;
            lb = -1.f; li = NN;
            #pragma unroll
            for (int u = 0; u < 6; ++u) {
                int j = tid + 256*u;
                if (j < NN && sreg[u] > lb) { lb = sreg[u]; li = j; }
            }
        }
    }
    if (tid == 0) {
        float s = 1.f;
        #pragma unroll
        for (int it = 0; it < TOPKK; ++it) s += adjw[v*13+it];
        float inv = 1.f/s;
        #pragma unroll
        for (int it = 0; it < TOPKK; ++it) adjw[v*13+it] *= inv;
        adji[v*13+12] = v;
        adjw[v*13+12] = inv;   // normalized self-loop
    }
}

__device__ __forceinline__ short8 ldfrag(const unsigned short* fr, int plane, int lane) {
    const uint4* p = (const uint4*)(fr + plane*512);
    return as_s8(p[lane]);
}

// ---------------- main ----------------
// 6-plane LDS (144 KB), 3 barriers/t:
//  planes {0,1}/{4,5}: h1 double-buffer (bf16) -> after B2 hold z (bf16 half-slots)
//                      -> after D hold y16 (bf16 half-slots, wave-local reuse)
//  planes {2,3}:       u1 (bf16) -> after B2 hold p (bf16 half-slots)
// Phases per t: B1 (gather u1) | b | B2 (MFMA: z,p; in-wave read-before-write) | b |
//               D (A(t+1) conv + lane-layout D1 gather + wave-local D2 MFMA + part RMW) | b
// z now round-trips bf16 (was fp32): absmax expected ~1.5-2.5e-3 (< 3.71e-3 threshold).
__global__ __launch_bounds__(NTH, 3) void main_kernel(
    const float* __restrict__ x,
    const float* __restrict__ ew, const float* __restrict__ eb,
    const float* __restrict__ adjw, const int* __restrict__ adji,
    const unsigned short* __restrict__ fr,
    float* __restrict__ part,
    const float* __restrict__ mb, const float* __restrict__ rb1)
{
    __shared__ uint4 feat[6][NPAD];  // 144384 B

    const int tid = threadIdx.x;
    const int lane = tid & 63;
    const int wid = tid >> 6;
    const int b = blockIdx.x >> 5;
    const int g = blockIdx.x & 31;
    const int t0 = (g*TLEN) >> 5;
    const int t1 = ((g+1)*TLEN) >> 5;
    const int n0 = lane & 15, q = lane >> 4;
    float* partBG = part + (size_t)(b*NG + g)*NN*16;

    // ---- prologue: A(t0) -> planes 0,1 ----
    #pragma unroll 1
    for (int s = 0; s < SN; ++s) {
        int v = tid + NTH*s;
        if (v < NN) {
            float xv[7];
            #pragma unroll
            for (int d = 0; d < 7; ++d) xv[d] = x[(b*TIN + t0 + d)*NN + v];
            float h[16];
            #pragma unroll
            for (int c = 0; c < 16; ++c) {
                float a = eb[c];
                #pragma unroll
                for (int d = 0; d < 7; ++d) a += ew[c*7+d]*xv[d];
                h[c] = a > 0.f ? a : 0.f;
            }
            feat[0][v] = make_uint4(pack2(h[0],h[1]), pack2(h[2],h[3]), pack2(h[4],h[5]), pack2(h[6],h[7]));
            feat[1][v] = make_uint4(pack2(h[8],h[9]), pack2(h[10],h[11]), pack2(h[12],h[13]), pack2(h[14],h[15]));
        }
    }
    __syncthreads();

    for (int t = t0; t < t1; ++t) {
        const int par = (t - t0) & 1;
        const int hc = par ? 4 : 0;   // current h1 planes (hc, hc+1)
        const int hn = par ? 0 : 4;   // next    h1 planes

        // ---- B1: u1 = A@h1 (raw weights, incl self-loop) -> planes 2,3 ----
        #pragma unroll 1
        for (int s = 0; s < SN; ++s) {
            int v = tid + NTH*s;
            if (v < NN) {
                float u1[16];
                #pragma unroll
                for (int c = 0; c < 16; ++c) u1[c] = 0.f;
                int base = v*13;
                #pragma unroll
                for (int j = 0; j < 13; ++j) {
                    int nb = adji[base+j];
                    float w = adjw[base+j];
                    uint4 b0 = feat[hc][nb], b1 = feat[hc+1][nb];
                    unsigned int uu[8] = {b0.x,b0.y,b0.z,b0.w,b1.x,b1.y,b1.z,b1.w};
                    #pragma unroll
                    for (int i = 0; i < 8; ++i) { u1[2*i] += w*unlo(uu[i]); u1[2*i+1] += w*unhi(uu[i]); }
                }
                feat[2][v] = make_uint4(pack2(u1[0],u1[1]), pack2(u1[2],u1[3]), pack2(u1[4],u1[5]), pack2(u1[6],u1[7]));
                feat[3][v] = make_uint4(pack2(u1[8],u1[9]), pack2(u1[10],u1[11]), pack2(u1[12],u1[13]), pack2(u1[14],u1[15]));
            }
        }
        __syncthreads();

        // ---- B2 (MFMA): z = [W1|U]@[h1;u1] -> bf16 half-slots over h1 planes;
        //                 p = V2@u1 -> bf16 half-slots over u1 planes.
        //      In-wave: all DS reads issue before DS writes (lockstep) -> safe in-place. ----
        {
            short8 a1h = ldfrag(fr, 0, lane), a1l = ldfrag(fr, 1, lane);
            short8 a2h = ldfrag(fr, 2, lane), a2l = ldfrag(fr, 3, lane);
            ushort4* zH = (ushort4*)feat[hc + (q >> 1)];
            ushort4* pH = (ushort4*)feat[2  + (q >> 1)];
            #pragma unroll 1
            for (int T = wid; T < NTILE; T += 12) {
                int n = T*16 + n0;
                short8 bf  = as_s8(feat[(q < 2) ? (hc + q) : q][n]);  // K-quads: h1,h1,u1,u1
                short8 b2f = as_s8(feat[2 + (q & 1)][n]);             // u1 (upper-K weights 0)
                v4f z = {0.f,0.f,0.f,0.f}, p = {0.f,0.f,0.f,0.f};
                z = __builtin_amdgcn_mfma_f32_16x16x32_bf16(a1h, bf, z, 0, 0, 0);
                z = __builtin_amdgcn_mfma_f32_16x16x32_bf16(a1l, bf, z, 0, 0, 0);
                p = __builtin_amdgcn_mfma_f32_16x16x32_bf16(a2h, b2f, p, 0, 0, 0);
                p = __builtin_amdgcn_mfma_f32_16x16x32_bf16(a2l, b2f, p, 0, 0, 0);
                ushort4 zz; zz.x = f2bf(z[0]); zz.y = f2bf(z[1]); zz.z = f2bf(z[2]); zz.w = f2bf(z[3]);
                ushort4 pp; pp.x = f2bf(p[0]); pp.y = f2bf(p[1]); pp.z = f2bf(p[2]); pp.w = f2bf(p[3]);
                zH[n*2 + (q & 1)] = zz;   // z quad q of node n
                pH[n*2 + (q & 1)] = pp;   // p quad q of node n
            }
        }
        __syncthreads();

        // ---- D: A(t+1) -> hn planes ; lane-layout D1 (y16 = relu(mb+z+gather p))
        //         -> y16 half-slots over hc planes ; wave-local D2 MFMA ; part RMW ----
        if (t + 1 < t1) {
            #pragma unroll 1
            for (int s = 0; s < SN; ++s) {
                int v = tid + NTH*s;
                if (v < NN) {
                    float xv[7];
                    #pragma unroll
                    for (int d = 0; d < 7; ++d) xv[d] = x[(b*TIN + (t+1) + d)*NN + v];
                    float h[16];
                    #pragma unroll
                    for (int c = 0; c < 16; ++c) {
                        float a = eb[c];
                        #pragma unroll
                        for (int d = 0; d < 7; ++d) a += ew[c*7+d]*xv[d];
                        h[c] = a > 0.f ? a : 0.f;
                    }
                    feat[hn][v]   = make_uint4(pack2(h[0],h[1]), pack2(h[2],h[3]), pack2(h[4],h[5]), pack2(h[6],h[7]));
                    feat[hn+1][v] = make_uint4(pack2(h[8],h[9]), pack2(h[10],h[11]), pack2(h[12],h[13]), pack2(h[14],h[15]));
                }
            }
        }
        {
            short8 a3h = ldfrag(fr, 4, lane), a3l = ldfrag(fr, 5, lane);
            float mbq[4], rbq[4];
            #pragma unroll
            for (int r = 0; r < 4; ++r) { mbq[r] = mb[q*4+r]; rbq[r] = rb1[q*4+r]; }
            ushort4* zH = (ushort4*)feat[hc + (q >> 1)];
            const ushort4* pH = (const ushort4*)feat[2 + (q >> 1)];
            #pragma unroll 1
            for (int T = wid; T < NTILE; T += 12) {
                int n = T*16 + n0;
                ushort4 zz = zH[n*2 + (q & 1)];
                float y0 = mbq[0] + bf2f(zz.x);
                float y1 = mbq[1] + bf2f(zz.y);
                float y2 = mbq[2] + bf2f(zz.z);
                float y3 = mbq[3] + bf2f(zz.w);
                int base = (n < NN ? n : NN-1) * 13;   // clamp: keep adj/LDS reads in range
                #pragma unroll
                for (int j = 0; j < 13; ++j) {
                    int nb = adji[base+j];
                    float w = adjw[base+j];
                    ushort4 ps = pH[nb*2 + (q & 1)];
                    y0 += w*bf2f(ps.x); y1 += w*bf2f(ps.y);
                    y2 += w*bf2f(ps.z); y3 += w*bf2f(ps.w);
                }
                y0 = y0 > 0.f ? y0 : 0.f;  y1 = y1 > 0.f ? y1 : 0.f;
                y2 = y2 > 0.f ? y2 : 0.f;  y3 = y3 > 0.f ? y3 : 0.f;
                ushort4 yy; yy.x = f2bf(y0); yy.y = f2bf(y1); yy.z = f2bf(y2); yy.w = f2bf(y3);
                zH[n*2 + (q & 1)] = yy;   // y16 quad q -> same half-slot (wave-local reuse)
                // D2: B-frag k-quad q of y16-padded; q>=2 reads p planes (finite x zero weights)
                short8 bfY = as_s8(feat[(q < 2) ? (hc + q) : q][n]);
                v4f acc = {0.f,0.f,0.f,0.f};
                acc = __builtin_amdgcn_mfma_f32_16x16x32_bf16(a3h, bfY, acc, 0, 0, 0);
                acc = __builtin_amdgcn_mfma_f32_16x16x32_bf16(a3l, bfY, acc, 0, 0, 0);
                if (n < NN) {
                    float r0 = acc[0]+rbq[0], r1 = acc[1]+rbq[1], r2 = acc[2]+rbq[2], r3 = acc[3]+rbq[3];
                    r0 = r0 > 0.f ? r0 : 0.f;  r1 = r1 > 0.f ? r1 : 0.f;
                    r2 = r2 > 0.f ? r2 : 0.f;  r3 = r3 > 0.f ? r3 : 0.f;
                    float4* pp = (float4*)(partBG + (size_t)n*16 + q*4);
                    if (t == t0) {
                        *pp = make_float4(r0, r1, r2, r3);
                    } else {
                        float4 o = *pp;
                        *pp = make_float4(o.x+r0, o.y+r1, o.z+r2, o.w+r3);
                    }
                }
            }
        }
        __syncthreads();   // next B1 reads hn planes + writes planes 2,3 (read by D)
    }
}

// ---------------- reduce1: sum over 32 g (coalesced), scale 1/162 ----------------
__global__ __launch_bounds__(256) void reduce1_kernel(const float* __restrict__ part,
                                                      float* __restrict__ s16buf)
{
    int idx = blockIdx.x*256 + threadIdx.x;     // over (b*NN+v)*16+c
    if (idx >= BB*NN*16) return;
    int c = idx & 15;
    int rest = idx >> 4;
    int v = rest % NN;
    int b = rest / NN;
    float s = 0.f;
    #pragma unroll
    for (int g = 0; g < NG; ++g)
        s += part[((size_t)(b*NG + g)*NN + v)*16 + c];
    s16buf[idx] = s * (1.0f/TLEN);
}

// ---------------- reduce2: out = rw2 @ s16 + rb2 ----------------
__global__ __launch_bounds__(256) void reduce2_kernel(const float* __restrict__ s16buf,
                                                      const float* __restrict__ rw2,
                                                      const float* __restrict__ rb2,
                                                      float* __restrict__ out)
{
    int idx = blockIdx.x*256 + threadIdx.x;     // over b*NN+v
    if (idx >= BB*NN) return;
    int v = idx % NN;
    int b = idx / NN;
    const float4* sp = (const float4*)(s16buf + (size_t)idx*16);
    float4 s0 = sp[0], s1 = sp[1], s2 = sp[2], s3 = sp[3];
    float s16[16] = {s0.x,s0.y,s0.z,s0.w, s1.x,s1.y,s1.z,s1.w,
                     s2.x,s2.y,s2.z,s2.w, s3.x,s3.y,s3.z,s3.w};
    #pragma unroll
    for (int o = 0; o < TOUTC; ++o) {
        float a = rb2[o];
        #pragma unroll
        for (int c = 0; c < 16; ++c) a += rw2[o*16+c]*s16[c];
        out[(b*TOUTC + o)*NN + v] = a;
    }
}

extern "C" void kernel_launch(void* const* d_in, const int* in_sizes, int n_in,
                              void* d_out, int out_size, void* d_ws, size_t ws_size,
                              hipStream_t stream)
{
    const float* x   = (const float*)d_in[0];
    const float* pw  = (const float*)d_in[1];
    const float* pb  = (const float*)d_in[2];
    const float* tw2 = (const float*)d_in[3];
    const float* tb2 = (const float*)d_in[4];
    const float* tw3 = (const float*)d_in[5];
    const float* tb3 = (const float*)d_in[6];
    const float* tw6 = (const float*)d_in[7];
    const float* tb6 = (const float*)d_in[8];
    const float* tw7 = (const float*)d_in[9];
    const float* tb7 = (const float*)d_in[10];
    const float* e1  = (const float*)d_in[11];
    const float* e2  = (const float*)d_in[12];
    const float* gw1 = (const float*)d_in[13];
    const float* gb1 = (const float*)d_in[14];
    const float* gw2 = (const float*)d_in[15];
    const float* gb2 = (const float*)d_in[16];
    const float* mw  = (const float*)d_in[17];
    const float* mb  = (const float*)d_in[18];
    const float* rw1 = (const float*)d_in[19];
    const float* rb1 = (const float*)d_in[20];
    const float* rw2 = (const float*)d_in[21];
    const float* rb2 = (const float*)d_in[22];
    float* ws  = (float*)d_ws;
    float* out = (float*)d_out;

    prep_kernel<<<(NN + 255)/256, 256, 0, stream>>>(e1,e2,gw1,gb1,gw2,gb2,pw,pb,
                                                    tw2,tb2,tw3,tb3,tw6,tb6,tw7,tb7,
                                                    mw, rw1, ws);
    graph_kernel<<<NN, 256, 0, stream>>>(ws + OFF_M1, ws + OFF_M2,
                                         ws + OFF_M1T, ws + OFF_M2T,
                                         ws + OFF_ADJW, (int*)ws + OFF_ADJI);
    main_kernel<<<BB*NG, NTH, 0, stream>>>(x, ws + OFF_EW, ws + OFF_EB,
                                           ws + OFF_ADJW, (const int*)ws + OFF_ADJI,
                                           (const unsigned short*)(ws + OFF_FR),
                                           ws + OFF_PART, mb, rb1);
    reduce1_kernel<<<(BB*NN*16 + 255)/256, 256, 0, stream>>>(ws + OFF_PART, ws + OFF_S16);
    reduce2_kernel<<<(BB*NN + 255)/256, 256, 0, stream>>>(ws + OFF_S16, rw2, rb2, out);
}